// Round 4
// baseline (245.436 us; speedup 1.0000x reference)
//
#include <hip/hip_runtime.h>
#include <hip/hip_bf16.h>

#define E 768
#define HD 64
#define NH 12
#define BSZ 2
#define SEQ 2048
#define M_ROWS (BSZ * SEQ)   // 4096
#define BH (BSZ * NH)        // 24

#define LOG2E 1.44269504f
#define QSCALE 0.18033688f   // 0.125 * log2e folded into Q
#define MSHIFT 16.0f         // fixed exponent shift (folded into biasP)

typedef float f4_t __attribute__((ext_vector_type(4)));
typedef float f32x16 __attribute__((ext_vector_type(16)));
typedef __bf16 bf8_t __attribute__((ext_vector_type(8)));
typedef unsigned short us8_t __attribute__((ext_vector_type(8)));
typedef unsigned short us4_t __attribute__((ext_vector_type(4)));

__device__ inline unsigned short f2bf(float f) {
  union { float f; unsigned u; } v; v.f = f;
  unsigned u = v.u + 0x7FFFu + ((v.u >> 16) & 1u);
  return (unsigned short)(u >> 16);
}

__device__ inline float ex2(float x) { return __builtin_amdgcn_exp2f(x); }

// pack two fp32 -> two bf16 in one v_perm (round-half-up) — R1-proven
__device__ inline unsigned pk2(float a, float b) {
  union { float f; unsigned u; } ua, ub;
  ua.f = a; ub.f = b;
  return __builtin_amdgcn_perm(ub.u + 0x8000u, ua.u + 0x8000u, 0x07060302u);
}

// swap a.lanes[32:63] <-> b.lanes[0:31] — R1-proven
__device__ inline void swap32(unsigned& a, unsigned& b) {
  asm volatile("v_permlane32_swap_b32 %0, %1" : "+v"(a), "+v"(b));
}

// ---------------- fused fp32 -> bf16 convert: X, weights, BIAS (permuted) -----
// blocks: [0,1536) X | [1536,2688) weights | [2688,2712) bias rows
// bias layout: [bh][tile(32)][64] f32, permuted to 32x32 MFMA C order,
//   value = LOG2E*(beta*bias + beta_bias) - MSHIFT
__global__ __launch_bounds__(256) void cvt_all(
    const float* __restrict__ X, const float* __restrict__ Wq,
    const float* __restrict__ Wk, const float* __restrict__ Wv,
    const float* __restrict__ Wo, const float* __restrict__ abias,
    const float* __restrict__ betaP, const float* __restrict__ bbiasP,
    unsigned short* __restrict__ Xbf, unsigned short* __restrict__ Wqkv,
    unsigned short* __restrict__ Wobf, float* __restrict__ biasPf) {
  const int nW = E * E;  // 589824
  int id = blockIdx.x;
  if (id < 2688) {
    const float* src;
    unsigned short* dst;
    float scale = 1.0f;
    int base;
    if (id < 1536) {
      src = X; dst = Xbf; base = id * 2048;
    } else {
      int r = id - 1536;
      int k = r / 288;
      int rb = r - k * 288;
      base = rb * 2048;
      if (k == 0)      { src = Wq; dst = Wqkv;          scale = QSCALE; }
      else if (k == 1) { src = Wk; dst = Wqkv + nW;     }
      else if (k == 2) { src = Wv; dst = Wqkv + 2 * nW; }
      else             { src = Wo; dst = Wobf;          }
    }
    int i = base + threadIdx.x * 8;
    const float4* s = (const float4*)(src + i);
    float4 a = s[0], b = s[1];
    us8_t o;
    o[0] = f2bf(a.x * scale); o[1] = f2bf(a.y * scale);
    o[2] = f2bf(a.z * scale); o[3] = f2bf(a.w * scale);
    o[4] = f2bf(b.x * scale); o[5] = f2bf(b.y * scale);
    o[6] = f2bf(b.z * scale); o[7] = f2bf(b.w * scale);
    *(us8_t*)(dst + i) = o;
    return;
  }
  {
    // bias: one bh row per block, permuted f32
    int bh = id - 2688;
    int s0 = threadIdx.x * 8;
    const float4* s = (const float4*)(abias + (size_t)bh * 2048 + s0);
    float4 a = s[0], c = s[1];
    float bv = LOG2E * betaP[0];
    float bc = LOG2E * bbiasP[0] - MSHIFT;
    int tile = s0 >> 6, kk = s0 & 63;
    int base = bh * 2048 + tile * 64 + (kk >> 5) * 32 + ((kk & 31) >> 3) * 4;
    f4_t lo = {fmaf(bv, a.x, bc), fmaf(bv, a.y, bc), fmaf(bv, a.z, bc), fmaf(bv, a.w, bc)};
    f4_t hi4 = {fmaf(bv, c.x, bc), fmaf(bv, c.y, bc), fmaf(bv, c.z, bc), fmaf(bv, c.w, bc)};
    *(f4_t*)(biasPf + base) = lo;
    *(f4_t*)(biasPf + base + 16) = hi4;
  }
}

// ---------------- fused QKV GEMM: double-buffered LDS, 1 barrier per k-step ---
__global__ __launch_bounds__(256) void gemm_qkv(
    const unsigned short* __restrict__ A, const unsigned short* __restrict__ Bw,
    const float* __restrict__ bq, const float* __restrict__ bk, const float* __restrict__ bv,
    unsigned short* __restrict__ Qb, unsigned short* __restrict__ Kb,
    unsigned short* __restrict__ Vtb) {
  __shared__ unsigned short Alds[2][64 * 64];    // 2 x 8 KB
  __shared__ unsigned short Blds[2][128 * 64];   // 2 x 16 KB
  const int w = threadIdx.x >> 6, lane = threadIdx.x & 63;
  const int quad = lane >> 4, l15 = lane & 15;
  const int rowBase = blockIdx.x * 64;
  const int colBase = blockIdx.y * 128;
  const int wr = (w & 1) * 32, wc = (w >> 1) * 64;
  f4_t acc[2][4] = {};
  const int swz = l15 & 7;

#define STAGE_QKV(BUF, K0)                                                       \
  {                                                                              \
    const int kk0_ = (K0);                                                       \
    for (int c = 0; c < 2; ++c) {                                                \
      int s = c * 256 + w * 64 + lane;                                           \
      int r = s >> 3, col = ((s & 7) ^ (r & 7)) * 8;                             \
      const unsigned short* ga = A + (size_t)(rowBase + r) * E + kk0_ + col;     \
      __builtin_amdgcn_global_load_lds(                                          \
          (const __attribute__((address_space(1))) void*)ga,                     \
          (__attribute__((address_space(3))) void*)&Alds[BUF][c * 2048 + w * 512], 16, 0, 0); \
    }                                                                            \
    for (int c = 0; c < 4; ++c) {                                                \
      int s = c * 256 + w * 64 + lane;                                           \
      int r = s >> 3, col = ((s & 7) ^ (r & 7)) * 8;                             \
      const unsigned short* gb = Bw + (size_t)(colBase + r) * E + kk0_ + col;    \
      __builtin_amdgcn_global_load_lds(                                          \
          (const __attribute__((address_space(1))) void*)gb,                     \
          (__attribute__((address_space(3))) void*)&Blds[BUF][c * 2048 + w * 512], 16, 0, 0); \
    }                                                                            \
  }

  STAGE_QKV(0, 0);
  __builtin_amdgcn_s_waitcnt(0);
  __syncthreads();   // buf0 ready
  for (int t = 0; t < 12; ++t) {
    const int cur = t & 1;
    if (t < 11) STAGE_QKV(cur ^ 1, (t + 1) * 64);
    bf8_t af[2][2], bfr[4][2];
#pragma unroll
    for (int mi = 0; mi < 2; ++mi)
#pragma unroll
      for (int ks = 0; ks < 2; ++ks)
        af[mi][ks] = *(const bf8_t*)&Alds[cur][(wr + mi * 16 + l15) * 64 + (((ks * 4 + quad) ^ swz) << 3)];
#pragma unroll
    for (int ni = 0; ni < 4; ++ni)
#pragma unroll
      for (int ks = 0; ks < 2; ++ks)
        bfr[ni][ks] = *(const bf8_t*)&Blds[cur][(wc + ni * 16 + l15) * 64 + (((ks * 4 + quad) ^ swz) << 3)];
#pragma unroll
    for (int ks = 0; ks < 2; ++ks)
#pragma unroll
      for (int mi = 0; mi < 2; ++mi)
#pragma unroll
        for (int ni = 0; ni < 4; ++ni)
          acc[mi][ni] = __builtin_amdgcn_mfma_f32_16x16x32_bf16(af[mi][ks], bfr[ni][ks], acc[mi][ni], 0, 0, 0);
    __builtin_amdgcn_s_waitcnt(0);   // drain next-tile loads (overlapped with MFMA above)
    __syncthreads();
  }
#undef STAGE_QKV

  const int which = colBase / E;
  if (which < 2) {
    const float* biasP = (which == 0) ? bq : bk;
    unsigned short* dst = (which == 0) ? Qb : Kb;
    const float bscale = (which == 0) ? QSCALE : 1.0f;
    const int cnBase = colBase - which * E + wc;
    const int h = cnBase >> 6;
    float biasv[4];
#pragma unroll
    for (int ni = 0; ni < 4; ++ni) biasv[ni] = biasP[cnBase + ni * 16 + l15] * bscale;
    unsigned short* T = &Blds[0][0] + w * 1024;
    const int row = lane >> 2, colE = (lane & 3) * 16;
#pragma unroll
    for (int mi = 0; mi < 2; ++mi) {
#pragma unroll
      for (int ni = 0; ni < 4; ++ni)
#pragma unroll
        for (int r = 0; r < 4; ++r)
          T[(quad * 4 + r) * 64 + ni * 16 + l15] = f2bf(acc[mi][ni][r] + biasv[ni]);
      us8_t o0 = *(const us8_t*)&T[row * 64 + colE];
      us8_t o1 = *(const us8_t*)&T[row * 64 + colE + 8];
      int gm = rowBase + wr + mi * 16 + row;
      int b = gm >> 11, t = gm & 2047;
      unsigned short* drow = dst + ((size_t)(b * NH + h) * SEQ + t) * HD;
      *(us8_t*)&drow[colE] = o0;
      *(us8_t*)&drow[colE + 8] = o1;
    }
  } else {
#pragma unroll
    for (int mi = 0; mi < 2; ++mi) {
#pragma unroll
      for (int ni = 0; ni < 4; ++ni) {
        int cn = colBase - 2 * E + wc + ni * 16 + l15;
        int h = cn >> 6, d = cn & 63;
        float bias = bv[cn];
        int gm0 = rowBase + wr + mi * 16 + quad * 4;
        int b = gm0 >> 11, t = gm0 & 2047;
        us4_t o4;
#pragma unroll
        for (int r = 0; r < 4; ++r) o4[r] = f2bf(acc[mi][ni][r] + bias);
        *(us4_t*)&Vtb[((size_t)(b * NH + h) * HD + d) * SEQ + t] = o4;
      }
    }
  }
}

// ---------------- flash attention v14: v13 structure, R1-proven arithmetic ----
// (1) S-accumulator = bias + LOG2E*mask as MFMA C-in, via SCALAR fmaf (the
//     inline-asm v_pk_* of v13 had wrong packed semantics -> 5.9e-2 absmax);
// (2) mask read directly as f32 (cvt mask pass deleted);
// (3) P pack via R1-proven pk2 + permlane32_swap; scalar L accumulation.
__device__ inline void initS(f32x16& SA, const float* bp, f4_t m0, f4_t m1,
                             f4_t m2, f4_t m3) {
#pragma unroll
  for (int g = 0; g < 4; ++g) {
    f4_t mg = (g == 0) ? m0 : (g == 1) ? m1 : (g == 2) ? m2 : m3;
    f4_t bw = *(const f4_t*)(bp + g * 4);
#pragma unroll
    for (int j = 0; j < 4; ++j) SA[4 * g + j] = fmaf(LOG2E, mg[j], bw[j]);
  }
}

__device__ inline void packP(f32x16& SA, float& L, bf8_t& F0, bf8_t& F1) {
#pragma unroll
  for (int r = 0; r < 16; ++r) {
    SA[r] = ex2(SA[r]);
    L += SA[r];
  }
  unsigned u0 = pk2(SA[0], SA[1]), u1 = pk2(SA[2], SA[3]);
  unsigned u2 = pk2(SA[4], SA[5]), u3 = pk2(SA[6], SA[7]);
  unsigned u4 = pk2(SA[8], SA[9]), u5 = pk2(SA[10], SA[11]);
  unsigned u6 = pk2(SA[12], SA[13]), u7 = pk2(SA[14], SA[15]);
  swap32(u0, u2); swap32(u1, u3); swap32(u4, u6); swap32(u5, u7);
  union { unsigned u[4]; bf8_t b; } fa, fb;
  fa.u[0] = u0; fa.u[1] = u1; fa.u[2] = u2; fa.u[3] = u3;
  fb.u[0] = u4; fb.u[1] = u5; fb.u[2] = u6; fb.u[3] = u7;
  F0 = fa.b; F1 = fb.b;
}

__global__ __launch_bounds__(256, 3) void flash_attn14(
    const unsigned short* __restrict__ Qb, const unsigned short* __restrict__ Kb,
    const unsigned short* __restrict__ Vt, const float* __restrict__ maskF,
    const float* __restrict__ biasPf, unsigned short* __restrict__ attn) {
  __shared__ __align__(16) char smem[40960];
  const int tid = threadIdx.x;
  const int w = tid >> 6, lane = tid & 63;
  const int l31 = lane & 31, hi = lane >> 5;
  const int p = w >> 1, qw = (w & 1) * 32;
  const int id = blockIdx.x;
  const int h = id >> 6;            // 0..11
  const int qb = id & 63;
  const int qt = qb >> 1, b = qb & 1;
  const int bh = b * NH + h;
  const int q0 = qt * 64;
  const int q = q0 + qw + l31;      // this lane's query (column of S^T)

  unsigned short* KldsP = (unsigned short*)(smem + p * 16384);  // [64 key][64 d] swizzled
  unsigned short* VldsP = KldsP + 4096;                         // [64 d][64 key] swizzled
  float* biasF = (float*)(smem + 32768);                        // [2048] permuted f32

  {
    const float* srcB = biasPf + bh * 2048 + tid * 8;
    *(f4_t*)&biasF[tid * 8] = *(const f4_t*)srcB;
    *(f4_t*)&biasF[tid * 8 + 4] = *(const f4_t*)(srcB + 4);
  }

  bf8_t qf[4];
  {
    const unsigned short* qbase = Qb + ((size_t)bh * SEQ + q) * HD + hi * 8;
#pragma unroll
    for (int dk = 0; dk < 4; ++dk) qf[dk] = *(const bf8_t*)(qbase + dk * 16);
  }

  const int li = (w & 1) * 64 + lane;
  const int r0 = li >> 3, cc = li & 7;
  const int dstOff = r0 * 64 + ((cc ^ (r0 & 7)) << 3);
  const unsigned short* kb0 = Kb + (size_t)bh * SEQ * HD + (p * 1024 + r0) * 64 + cc * 8;
  const unsigned short* VtG = Vt + (size_t)bh * HD * SEQ;
  const unsigned short* vb0 = VtG + (size_t)r0 * SEQ + p * 1024 + cc * 8;
  const float* mp = maskF + ((size_t)b * SEQ + q) * SEQ + p * 1024 + hi * 4;

  us8_t kpf0, kpf1, kpf2, kpf3, vpf0, vpf1, vpf2, vpf3;
  f4_t mq0, mq1, mq2, mq3, mq4, mq5, mq6, mq7;

#define PF_KV()                                                               \
  asm volatile("global_load_dwordx4 %0, %8, off\n\t"                          \
               "global_load_dwordx4 %1, %8, off offset:2048\n\t"              \
               "global_load_dwordx4 %2, %9, off\n\t"                          \
               "global_load_dwordx4 %3, %9, off offset:2048\n\t"              \
               "global_load_dwordx4 %4, %10, off\n\t"                         \
               "global_load_dwordx4 %5, %11, off\n\t"                         \
               "global_load_dwordx4 %6, %12, off\n\t"                         \
               "global_load_dwordx4 %7, %13, off"                             \
               : "=&v"(kpf0), "=&v"(kpf1), "=&v"(kpf2), "=&v"(kpf3),          \
                 "=&v"(vpf0), "=&v"(vpf1), "=&v"(vpf2), "=&v"(vpf3)           \
               : "v"(kb0), "v"(kb0 + 2048), "v"(vb0), "v"(vb0 + 16 * SEQ),    \
                 "v"(vb0 + 32 * SEQ), "v"(vb0 + 48 * SEQ))

#define PF_M()                                                                \
  asm volatile("global_load_dwordx4 %0, %8, off\n\t"                          \
               "global_load_dwordx4 %1, %8, off offset:32\n\t"                \
               "global_load_dwordx4 %2, %8, off offset:64\n\t"                \
               "global_load_dwordx4 %3, %8, off offset:96\n\t"                \
               "global_load_dwordx4 %4, %8, off offset:128\n\t"               \
               "global_load_dwordx4 %5, %8, off offset:160\n\t"               \
               "global_load_dwordx4 %6, %8, off offset:192\n\t"               \
               "global_load_dwordx4 %7, %8, off offset:224"                   \
               : "=&v"(mq0), "=&v"(mq1), "=&v"(mq2), "=&v"(mq3),              \
                 "=&v"(mq4), "=&v"(mq5), "=&v"(mq6), "=&v"(mq7)               \
               : "v"(mp))

  PF_KV();
  PF_M();

  f32x16 Oacc0 = {}, Oacc1 = {};   // O^T[d][q], dblk 0/1
  float Lacc = 0.0f;
  const int swzA = l31 & 7;

  for (int it = 0; it < 16; ++it) {
    asm volatile("s_waitcnt vmcnt(8)"   // K/V done; 8 mask loads may still fly
                 : "+v"(kpf0), "+v"(kpf1), "+v"(kpf2), "+v"(kpf3),
                   "+v"(vpf0), "+v"(vpf1), "+v"(vpf2), "+v"(vpf3));
    __syncthreads();
    {
      us8_t* kd = (us8_t*)(KldsP + dstOff);
      kd[0] = kpf0; kd[128] = kpf1; kd[256] = kpf2; kd[384] = kpf3;
      us8_t* vd = (us8_t*)(VldsP + dstOff);
      vd[0] = vpf0; vd[128] = vpf1; vd[256] = vpf2; vd[384] = vpf3;
    }
    __syncthreads();

    if (it < 15) {
      kb0 += 4096; vb0 += 64;
      PF_KV();
      asm volatile("s_waitcnt vmcnt(8)"  // drains 8 old mask loads, keeps 8 new K/V
                   : "+v"(mq0), "+v"(mq1), "+v"(mq2), "+v"(mq3),
                     "+v"(mq4), "+v"(mq5), "+v"(mq6), "+v"(mq7));
    } else {
      asm volatile("s_waitcnt vmcnt(0)"
                   : "+v"(mq0), "+v"(mq1), "+v"(mq2), "+v"(mq3),
                     "+v"(mq4), "+v"(mq5), "+v"(mq6), "+v"(mq7));
    }

    // S-accumulator init = bias + LOG2E*mask (MFMA C-in), scalar fmaf
    const float* bp = biasF + ((p << 4) + it) * 64 + (hi << 4);
    f32x16 s0, s1;
    initS(s0, bp, mq0, mq1, mq2, mq3);
    initS(s1, bp + 32, mq4, mq5, mq6, mq7);

    if (it < 15) { mp += 64; PF_M(); }

    // QK^T: S^T[key][q]
    __builtin_amdgcn_s_setprio(1);
#pragma unroll
    for (int dk = 0; dk < 4; ++dk) {
      const int co = ((dk * 2 + hi) ^ swzA) << 3;
      bf8_t k0 = *(const bf8_t*)(KldsP + l31 * 64 + co);
      bf8_t k1 = *(const bf8_t*)(KldsP + (32 + l31) * 64 + co);
      s0 = __builtin_amdgcn_mfma_f32_32x32x16_bf16(k0, qf[dk], s0, 0, 0, 0);
      s1 = __builtin_amdgcn_mfma_f32_32x32x16_bf16(k1, qf[dk], s1, 0, 0, 0);
    }
    __builtin_amdgcn_s_setprio(0);

    // exp2 + in-register P -> bf16 B-fragments
    bf8_t pfr0, pfr1, pfr2, pfr3;
    packP(s0, Lacc, pfr0, pfr1);
    packP(s1, Lacc, pfr2, pfr3);

    // PV: O^T += V^T * P^T
    __builtin_amdgcn_s_setprio(1);
#pragma unroll
    for (int ks = 0; ks < 4; ++ks) {
      const int co = ((ks * 2 + hi) ^ swzA) << 3;
      bf8_t v0 = *(const bf8_t*)(VldsP + l31 * 64 + co);
      bf8_t v1 = *(const bf8_t*)(VldsP + (32 + l31) * 64 + co);
      bf8_t pp = ks == 0 ? pfr0 : ks == 1 ? pfr1 : ks == 2 ? pfr2 : pfr3;
      Oacc0 = __builtin_amdgcn_mfma_f32_32x32x16_bf16(v0, pp, Oacc0, 0, 0, 0);
      Oacc1 = __builtin_amdgcn_mfma_f32_32x32x16_bf16(v1, pp, Oacc1, 0, 0, 0);
    }
    __builtin_amdgcn_s_setprio(0);
  }
#undef PF_KV
#undef PF_M

  // -------- combine pair partials via LDS (additive: fixed shift, no max) ------
  __syncthreads();   // all K/V/bias LDS reads done; overlay Of[2][64][65] f32
  {
    float* OfP = (float*)smem + p * (64 * 65);
    const int qr = (qw + l31) * 65;
#pragma unroll
    for (int r = 0; r < 16; ++r) {
      int d = (r & 3) + 8 * (r >> 2) + 4 * hi;
      OfP[qr + d] = Oacc0[r];
      OfP[qr + 32 + d] = Oacc1[r];
    }
    float Lf = Lacc + __shfl_xor(Lacc, 32);
    if (hi == 0) OfP[qr + 64] = Lf;
  }
  __syncthreads();
  {
    const float* O0 = (const float*)smem;
    const float* O1 = O0 + 64 * 65;
    const int ql = tid >> 2, dc = tid & 3;
    const int qr = ql * 65;
    float inv = 1.0f / (O0[qr + 64] + O1[qr + 64]);
    unsigned short* orow = attn + ((size_t)b * SEQ + q0 + ql) * E + h * HD + dc * 16;
    us8_t o0, o1;
#pragma unroll
    for (int i = 0; i < 8; ++i)
      o0[i] = f2bf((O0[qr + dc * 16 + i] + O1[qr + dc * 16 + i]) * inv);
#pragma unroll
    for (int i = 0; i < 8; ++i)
      o1[i] = f2bf((O0[qr + dc * 16 + 8 + i] + O1[qr + dc * 16 + 8 + i]) * inv);
    *(us8_t*)orow = o0;
    *(us8_t*)(orow + 8) = o1;
  }
}

// ---------------- output projection GEMM: double-buffered LDS -----------------
__global__ __launch_bounds__(256) void gemm_out(
    const unsigned short* __restrict__ A, const unsigned short* __restrict__ Bw,
    const float* __restrict__ bo, float* __restrict__ out) {
  __shared__ unsigned short Alds[2][64 * 64];
  __shared__ unsigned short Blds[2][64 * 64];
  const int w = threadIdx.x >> 6, lane = threadIdx.x & 63;
  const int quad = lane >> 4, l15 = lane & 15;
  const int rowBase = blockIdx.x * 64;
  const int colBase = blockIdx.y * 64;
  const int wr = (w & 1) * 32, wc = (w >> 1) * 32;
  f4_t acc[2][2] = {};
  const int swz = l15 & 7;

#define STAGE_OUT(BUF, K0)                                                       \
  {                                                                              \
    const int kk0_ = (K0);                                                       \
    for (int c = 0; c < 2; ++c) {                                                \
      int s = c * 256 + w * 64 + lane;                                           \
      int r = s >> 3, col = ((s & 7) ^ (r & 7)) * 8;                             \
      const unsigned short* ga = A + (size_t)(rowBase + r) * E + kk0_ + col;     \
      __builtin_amdgcn_global_load_lds(                                          \
          (const __attribute__((address_space(1))) void*)ga,                     \
          (__attribute__((address_space(3))) void*)&Alds[BUF][c * 2048 + w * 512], 16, 0, 0); \
      const unsigned short* gb = Bw + (size_t)(colBase + r) * E + kk0_ + col;    \
      __builtin_amdgcn_global_load_lds(                                          \
          (const __attribute__((address_space(1))) void*)gb,                     \
          (__attribute__((address_space(3))) void*)&Blds[BUF][c * 2048 + w * 512], 16, 0, 0); \
    }                                                                            \
  }

  STAGE_OUT(0, 0);
  __builtin_amdgcn_s_waitcnt(0);
  __syncthreads();
  for (int t = 0; t < 12; ++t) {
    const int cur = t & 1;
    if (t < 11) STAGE_OUT(cur ^ 1, (t + 1) * 64);
    bf8_t af[2][2], bfr[2][2];
#pragma unroll
    for (int mi = 0; mi < 2; ++mi)
#pragma unroll
      for (int ks = 0; ks < 2; ++ks)
        af[mi][ks] = *(const bf8_t*)&Alds[cur][(wr + mi * 16 + l15) * 64 + (((ks * 4 + quad) ^ swz) << 3)];
#pragma unroll
    for (int ni = 0; ni < 2; ++ni)
#pragma unroll
      for (int ks = 0; ks < 2; ++ks)
        bfr[ni][ks] = *(const bf8_t*)&Blds[cur][(wc + ni * 16 + l15) * 64 + (((ks * 4 + quad) ^ swz) << 3)];
#pragma unroll
    for (int ks = 0; ks < 2; ++ks)
#pragma unroll
      for (int mi = 0; mi < 2; ++mi)
#pragma unroll
        for (int ni = 0; ni < 2; ++ni)
          acc[mi][ni] = __builtin_amdgcn_mfma_f32_16x16x32_bf16(af[mi][ks], bfr[ni][ks], acc[mi][ni], 0, 0, 0);
    __builtin_amdgcn_s_waitcnt(0);
    __syncthreads();
  }
#undef STAGE_OUT

#pragma unroll
  for (int mi = 0; mi < 2; ++mi) {
#pragma unroll
    for (int ni = 0; ni < 2; ++ni) {
      int gn = colBase + wc + ni * 16 + l15;
      float bias = bo[gn];
#pragma unroll
      for (int r = 0; r < 4; ++r) {
        int gm = rowBase + wr + mi * 16 + quad * 4 + r;
        out[(size_t)gm * E + gn] = acc[mi][ni][r] + bias;
      }
    }
  }
}

extern "C" void kernel_launch(void* const* d_in, const int* in_sizes, int n_in,
                              void* d_out, int out_size, void* d_ws, size_t ws_size,
                              hipStream_t stream) {
  const float* hidden = (const float*)d_in[0];
  const float* mask = (const float*)d_in[1];
  const float* abias = (const float*)d_in[2];
  const float* Wq = (const float*)d_in[3];
  const float* bq = (const float*)d_in[4];
  const float* Wk = (const float*)d_in[5];
  const float* bk = (const float*)d_in[6];
  const float* Wv = (const float*)d_in[7];
  const float* bv = (const float*)d_in[8];
  const float* Wo = (const float*)d_in[9];
  const float* bo = (const float*)d_in[10];
  const float* beta = (const float*)d_in[11];
  const float* betaBias = (const float*)d_in[12];
  float* out = (float*)d_out;

  char* ws = (char*)d_ws;
  unsigned short* Xbf = (unsigned short*)(ws);
  unsigned short* Wqkv = (unsigned short*)(ws + 6291456);
  unsigned short* Wobf = (unsigned short*)(ws + 9830400);
  unsigned short* Qbuf = (unsigned short*)(ws + 11010048);
  unsigned short* Kbuf = (unsigned short*)(ws + 17301504);
  unsigned short* Vtb = (unsigned short*)(ws + 23592960);
  float* BiasP = (float*)(ws + 46661632);   // 24*2048*4 = 192 KB
  unsigned short* Attn = Xbf;  // Xbf dead after gemm_qkv

  cvt_all<<<2712, 256, 0, stream>>>(hidden, Wq, Wk, Wv, Wo, abias, beta, betaBias,
                                    Xbf, Wqkv, Wobf, BiasP);
  gemm_qkv<<<dim3(64, 18), 256, 0, stream>>>(Xbf, Wqkv, bq, bk, bv, Qbuf, Kbuf, Vtb);
  flash_attn14<<<768, 256, 0, stream>>>(Qbuf, Kbuf, Vtb, mask, BiasP, Attn);
  gemm_out<<<dim3(64, 12), 256, 0, stream>>>(Attn, Wobf, bo, out);
}

// Round 5
// 200.751 us; speedup vs baseline: 1.2226x; 1.2226x over previous
//
#include <hip/hip_runtime.h>
#include <hip/hip_bf16.h>

#define E 768
#define HD 64
#define NH 12
#define BSZ 2
#define SEQ 2048
#define M_ROWS (BSZ * SEQ)   // 4096
#define BH (BSZ * NH)        // 24

#define LOG2E 1.44269504f
#define QSCALE 0.18033688f   // 0.125 * log2e folded into Q
#define MSHIFT 16.0f         // fixed exponent shift (folded into biasP)

typedef float f4_t __attribute__((ext_vector_type(4)));
typedef float f32x16 __attribute__((ext_vector_type(16)));
typedef __bf16 bf8_t __attribute__((ext_vector_type(8)));
typedef unsigned short us8_t __attribute__((ext_vector_type(8)));
typedef unsigned short us4_t __attribute__((ext_vector_type(4)));

__device__ inline unsigned short f2bf(float f) {
  union { float f; unsigned u; } v; v.f = f;
  unsigned u = v.u + 0x7FFFu + ((v.u >> 16) & 1u);
  return (unsigned short)(u >> 16);
}

__device__ inline float ex2(float x) { return __builtin_amdgcn_exp2f(x); }

// bf16 pair -> fp32 (low / high halves of a uint)
__device__ inline float bflo(unsigned u) { union { unsigned u; float f; } v; v.u = u << 16; return v.f; }
__device__ inline float bfhi(unsigned u) { union { unsigned u; float f; } v; v.u = u & 0xFFFF0000u; return v.f; }

// pack two fp32 -> two bf16 in one v_perm (round-half-up) — R1-proven
__device__ inline unsigned pk2(float a, float b) {
  union { float f; unsigned u; } ua, ub;
  ua.f = a; ub.f = b;
  return __builtin_amdgcn_perm(ub.u + 0x8000u, ua.u + 0x8000u, 0x07060302u);
}

// swap a.lanes[32:63] <-> b.lanes[0:31] — R1-proven
__device__ inline void swap32(unsigned& a, unsigned& b) {
  asm volatile("v_permlane32_swap_b32 %0, %1" : "+v"(a), "+v"(b));
}

// ---------------- fused fp32 -> bf16 convert: X, weights, MASK (perm), BIAS (perm)
// blocks: [0,1536) X | [1536,2688) weights | [2688,6784) mask | [6784,6808) bias
// permuted 32x32 MFMA C order: key kk -> idx = (kk>>5)*32 + ((kk>>2)&1)*16
//                                            + ((kk&31)>>3)*4 + (kk&3)
// mask layout:  [b][tile(32)][q(2048)][64] bf16, value = LOG2E*mask
// bias layout:  [bh][tile(32)][64] f32, value = LOG2E*(beta*bias + beta_bias) - MSHIFT
__global__ __launch_bounds__(256) void cvt_all(
    const float* __restrict__ X, const float* __restrict__ Wq,
    const float* __restrict__ Wk, const float* __restrict__ Wv,
    const float* __restrict__ Wo, const float* __restrict__ mask,
    const float* __restrict__ abias, const float* __restrict__ betaP,
    const float* __restrict__ bbiasP,
    unsigned short* __restrict__ Xbf, unsigned short* __restrict__ Wqkv,
    unsigned short* __restrict__ Wobf, unsigned short* __restrict__ maskbf,
    float* __restrict__ biasPf) {
  const int nW = E * E;  // 589824
  int id = blockIdx.x;
  if (id < 2688) {
    const float* src;
    unsigned short* dst;
    float scale = 1.0f;
    int base;
    if (id < 1536) {
      src = X; dst = Xbf; base = id * 2048;
    } else {
      int r = id - 1536;
      int k = r / 288;
      int rb = r - k * 288;
      base = rb * 2048;
      if (k == 0)      { src = Wq; dst = Wqkv;          scale = QSCALE; }
      else if (k == 1) { src = Wk; dst = Wqkv + nW;     }
      else if (k == 2) { src = Wv; dst = Wqkv + 2 * nW; }
      else             { src = Wo; dst = Wobf;          }
    }
    int i = base + threadIdx.x * 8;
    const float4* s = (const float4*)(src + i);
    float4 a = s[0], b = s[1];
    us8_t o;
    o[0] = f2bf(a.x * scale); o[1] = f2bf(a.y * scale);
    o[2] = f2bf(a.z * scale); o[3] = f2bf(a.w * scale);
    o[4] = f2bf(b.x * scale); o[5] = f2bf(b.y * scale);
    o[6] = f2bf(b.z * scale); o[7] = f2bf(b.w * scale);
    *(us8_t*)(dst + i) = o;
    return;
  }
  if (id < 6784) {
    // mask: one (b,q) row per block, 2048 s each, permuted + *LOG2E
    int rowid = id - 2688;             // b*2048 + q
    int bb = rowid >> 11, q = rowid & 2047;
    int s0 = threadIdx.x * 8;
    const float4* s = (const float4*)(mask + (size_t)rowid * 2048 + s0);
    float4 a = s[0], c = s[1];
    int tile = s0 >> 6, kk = s0 & 63;
    int base = ((bb * 32 + tile) * 2048 + q) * 64 + (kk >> 5) * 32 + ((kk & 31) >> 3) * 4;
    us4_t lo, hi4;
    lo[0] = f2bf(a.x * LOG2E); lo[1] = f2bf(a.y * LOG2E);
    lo[2] = f2bf(a.z * LOG2E); lo[3] = f2bf(a.w * LOG2E);
    hi4[0] = f2bf(c.x * LOG2E); hi4[1] = f2bf(c.y * LOG2E);
    hi4[2] = f2bf(c.z * LOG2E); hi4[3] = f2bf(c.w * LOG2E);
    *(us4_t*)(maskbf + base) = lo;        // ((kk>>2)&1)==0 half
    *(us4_t*)(maskbf + base + 16) = hi4;  // ((kk>>2)&1)==1 half
    return;
  }
  {
    // bias: one bh row per block, permuted f32
    int bh = id - 6784;
    int s0 = threadIdx.x * 8;
    const float4* s = (const float4*)(abias + (size_t)bh * 2048 + s0);
    float4 a = s[0], c = s[1];
    float bv = LOG2E * betaP[0];
    float bc = LOG2E * bbiasP[0] - MSHIFT;
    int tile = s0 >> 6, kk = s0 & 63;
    int base = bh * 2048 + tile * 64 + (kk >> 5) * 32 + ((kk & 31) >> 3) * 4;
    f4_t lo = {fmaf(bv, a.x, bc), fmaf(bv, a.y, bc), fmaf(bv, a.z, bc), fmaf(bv, a.w, bc)};
    f4_t hi4 = {fmaf(bv, c.x, bc), fmaf(bv, c.y, bc), fmaf(bv, c.z, bc), fmaf(bv, c.w, bc)};
    *(f4_t*)(biasPf + base) = lo;
    *(f4_t*)(biasPf + base + 16) = hi4;
  }
}

// ---------------- fused QKV GEMM: double-buffered LDS (unchanged, passing) ----
__global__ __launch_bounds__(256) void gemm_qkv(
    const unsigned short* __restrict__ A, const unsigned short* __restrict__ Bw,
    const float* __restrict__ bq, const float* __restrict__ bk, const float* __restrict__ bv,
    unsigned short* __restrict__ Qb, unsigned short* __restrict__ Kb,
    unsigned short* __restrict__ Vtb) {
  __shared__ unsigned short Alds[2][64 * 64];    // 2 x 8 KB
  __shared__ unsigned short Blds[2][128 * 64];   // 2 x 16 KB
  const int w = threadIdx.x >> 6, lane = threadIdx.x & 63;
  const int quad = lane >> 4, l15 = lane & 15;
  const int rowBase = blockIdx.x * 64;
  const int colBase = blockIdx.y * 128;
  const int wr = (w & 1) * 32, wc = (w >> 1) * 64;
  f4_t acc[2][4] = {};
  const int swz = l15 & 7;

#define STAGE_QKV(BUF, K0)                                                       \
  {                                                                              \
    const int kk0_ = (K0);                                                       \
    for (int c = 0; c < 2; ++c) {                                                \
      int s = c * 256 + w * 64 + lane;                                           \
      int r = s >> 3, col = ((s & 7) ^ (r & 7)) * 8;                             \
      const unsigned short* ga = A + (size_t)(rowBase + r) * E + kk0_ + col;     \
      __builtin_amdgcn_global_load_lds(                                          \
          (const __attribute__((address_space(1))) void*)ga,                     \
          (__attribute__((address_space(3))) void*)&Alds[BUF][c * 2048 + w * 512], 16, 0, 0); \
    }                                                                            \
    for (int c = 0; c < 4; ++c) {                                                \
      int s = c * 256 + w * 64 + lane;                                           \
      int r = s >> 3, col = ((s & 7) ^ (r & 7)) * 8;                             \
      const unsigned short* gb = Bw + (size_t)(colBase + r) * E + kk0_ + col;    \
      __builtin_amdgcn_global_load_lds(                                          \
          (const __attribute__((address_space(1))) void*)gb,                     \
          (__attribute__((address_space(3))) void*)&Blds[BUF][c * 2048 + w * 512], 16, 0, 0); \
    }                                                                            \
  }

  STAGE_QKV(0, 0);
  __builtin_amdgcn_s_waitcnt(0);
  __syncthreads();   // buf0 ready
  for (int t = 0; t < 12; ++t) {
    const int cur = t & 1;
    if (t < 11) STAGE_QKV(cur ^ 1, (t + 1) * 64);
    bf8_t af[2][2], bfr[4][2];
#pragma unroll
    for (int mi = 0; mi < 2; ++mi)
#pragma unroll
      for (int ks = 0; ks < 2; ++ks)
        af[mi][ks] = *(const bf8_t*)&Alds[cur][(wr + mi * 16 + l15) * 64 + (((ks * 4 + quad) ^ swz) << 3)];
#pragma unroll
    for (int ni = 0; ni < 4; ++ni)
#pragma unroll
      for (int ks = 0; ks < 2; ++ks)
        bfr[ni][ks] = *(const bf8_t*)&Blds[cur][(wc + ni * 16 + l15) * 64 + (((ks * 4 + quad) ^ swz) << 3)];
#pragma unroll
    for (int ks = 0; ks < 2; ++ks)
#pragma unroll
      for (int mi = 0; mi < 2; ++mi)
#pragma unroll
        for (int ni = 0; ni < 4; ++ni)
          acc[mi][ni] = __builtin_amdgcn_mfma_f32_16x16x32_bf16(af[mi][ks], bfr[ni][ks], acc[mi][ni], 0, 0, 0);
    __builtin_amdgcn_s_waitcnt(0);   // drain next-tile loads (overlapped with MFMA above)
    __syncthreads();
  }
#undef STAGE_QKV

  const int which = colBase / E;
  if (which < 2) {
    const float* biasP = (which == 0) ? bq : bk;
    unsigned short* dst = (which == 0) ? Qb : Kb;
    const float bscale = (which == 0) ? QSCALE : 1.0f;
    const int cnBase = colBase - which * E + wc;
    const int h = cnBase >> 6;
    float biasv[4];
#pragma unroll
    for (int ni = 0; ni < 4; ++ni) biasv[ni] = biasP[cnBase + ni * 16 + l15] * bscale;
    unsigned short* T = &Blds[0][0] + w * 1024;
    const int row = lane >> 2, colE = (lane & 3) * 16;
#pragma unroll
    for (int mi = 0; mi < 2; ++mi) {
#pragma unroll
      for (int ni = 0; ni < 4; ++ni)
#pragma unroll
        for (int r = 0; r < 4; ++r)
          T[(quad * 4 + r) * 64 + ni * 16 + l15] = f2bf(acc[mi][ni][r] + biasv[ni]);
      us8_t o0 = *(const us8_t*)&T[row * 64 + colE];
      us8_t o1 = *(const us8_t*)&T[row * 64 + colE + 8];
      int gm = rowBase + wr + mi * 16 + row;
      int b = gm >> 11, t = gm & 2047;
      unsigned short* drow = dst + ((size_t)(b * NH + h) * SEQ + t) * HD;
      *(us8_t*)&drow[colE] = o0;
      *(us8_t*)&drow[colE + 8] = o1;
    }
  } else {
#pragma unroll
    for (int mi = 0; mi < 2; ++mi) {
#pragma unroll
      for (int ni = 0; ni < 4; ++ni) {
        int cn = colBase - 2 * E + wc + ni * 16 + l15;
        int h = cn >> 6, d = cn & 63;
        float bias = bv[cn];
        int gm0 = rowBase + wr + mi * 16 + quad * 4;
        int b = gm0 >> 11, t = gm0 & 2047;
        us4_t o4;
#pragma unroll
        for (int r = 0; r < 4; ++r) o4[r] = f2bf(acc[mi][ni][r] + bias);
        *(us4_t*)&Vtb[((size_t)(b * NH + h) * HD + d) * SEQ + t] = o4;
      }
    }
  }
}

// ---------------- flash attention v15: v12 mask path + C-in init --------------
// vs v12: S = bias + mask written as MFMA C-in (kills 32 movs + 32 adds/iter);
// PF_KV issued right after the LDS barrier (more latency slack).
// vs v14: mask back to permuted bf16 (L2-resident; f32 doubled the per-XCD
// working set to 4MB = L2 size and thrashed -> 108us).
__device__ inline void initS(f32x16& SA, const float* bp, us8_t ma, us8_t mb) {
  union { us8_t s; unsigned u[4]; } ca, cb;
  ca.s = ma; cb.s = mb;
#pragma unroll
  for (int g = 0; g < 4; ++g) {
    f4_t bw = *(const f4_t*)(bp + g * 4);
    unsigned wl = (g < 2) ? ca.u[2 * g] : cb.u[2 * g - 4];
    unsigned wh = (g < 2) ? ca.u[2 * g + 1] : cb.u[2 * g - 3];
    SA[4 * g + 0] = bw[0] + bflo(wl);
    SA[4 * g + 1] = bw[1] + bfhi(wl);
    SA[4 * g + 2] = bw[2] + bflo(wh);
    SA[4 * g + 3] = bw[3] + bfhi(wh);
  }
}

__device__ inline void packP(f32x16& SA, float& L, bf8_t& F0, bf8_t& F1) {
#pragma unroll
  for (int r = 0; r < 16; ++r) {
    SA[r] = ex2(SA[r]);
    L += SA[r];
  }
  unsigned u0 = pk2(SA[0], SA[1]), u1 = pk2(SA[2], SA[3]);
  unsigned u2 = pk2(SA[4], SA[5]), u3 = pk2(SA[6], SA[7]);
  unsigned u4 = pk2(SA[8], SA[9]), u5 = pk2(SA[10], SA[11]);
  unsigned u6 = pk2(SA[12], SA[13]), u7 = pk2(SA[14], SA[15]);
  swap32(u0, u2); swap32(u1, u3); swap32(u4, u6); swap32(u5, u7);
  union { unsigned u[4]; bf8_t b; } fa, fb;
  fa.u[0] = u0; fa.u[1] = u1; fa.u[2] = u2; fa.u[3] = u3;
  fb.u[0] = u4; fb.u[1] = u5; fb.u[2] = u6; fb.u[3] = u7;
  F0 = fa.b; F1 = fb.b;
}

__global__ __launch_bounds__(256, 3) void flash_attn15(
    const unsigned short* __restrict__ Qb, const unsigned short* __restrict__ Kb,
    const unsigned short* __restrict__ Vt, const unsigned short* __restrict__ maskP,
    const float* __restrict__ biasPf, unsigned short* __restrict__ attn) {
  __shared__ __align__(16) char smem[40960];
  const int tid = threadIdx.x;
  const int w = tid >> 6, lane = tid & 63;
  const int l31 = lane & 31, hi = lane >> 5;
  const int p = w >> 1, qw = (w & 1) * 32;
  const int id = blockIdx.x;
  const int h = id >> 6;            // 0..11
  const int qb = id & 63;
  const int qt = qb >> 1, b = qb & 1;   // XCD = id%8 = qb%8 -> all 12 h share XCD
  const int bh = b * NH + h;
  const int q0 = qt * 64;
  const int q = q0 + qw + l31;      // this lane's query (column of S^T)

  unsigned short* KldsP = (unsigned short*)(smem + p * 16384);  // [64 key][64 d] swizzled
  unsigned short* VldsP = KldsP + 4096;                         // [64 d][64 key] swizzled
  float* biasF = (float*)(smem + 32768);                        // [2048] permuted f32

  {
    const float* srcB = biasPf + bh * 2048 + tid * 8;
    *(f4_t*)&biasF[tid * 8] = *(const f4_t*)srcB;
    *(f4_t*)&biasF[tid * 8 + 4] = *(const f4_t*)(srcB + 4);
  }

  bf8_t qf[4];
  {
    const unsigned short* qbase = Qb + ((size_t)bh * SEQ + q) * HD + hi * 8;
#pragma unroll
    for (int dk = 0; dk < 4; ++dk) qf[dk] = *(const bf8_t*)(qbase + dk * 16);
  }

  const int li = (w & 1) * 64 + lane;
  const int r0 = li >> 3, cc = li & 7;
  const int dstOff = r0 * 64 + ((cc ^ (r0 & 7)) << 3);
  const unsigned short* kb0 = Kb + (size_t)bh * SEQ * HD + (p * 1024 + r0) * 64 + cc * 8;
  const unsigned short* VtG = Vt + (size_t)bh * HD * SEQ;
  const unsigned short* vb0 = VtG + (size_t)r0 * SEQ + p * 1024 + cc * 8;
  const unsigned short* mpp = maskP + (((size_t)(b * 32 + p * 16) * 2048) + q) * 64 + hi * 16;

  us8_t kpf0, kpf1, kpf2, kpf3, vpf0, vpf1, vpf2, vpf3, mpf0, mpf1, mpf2, mpf3;

#define PF_KV()                                                               \
  asm volatile("global_load_dwordx4 %0, %8, off\n\t"                          \
               "global_load_dwordx4 %1, %8, off offset:2048\n\t"              \
               "global_load_dwordx4 %2, %9, off\n\t"                          \
               "global_load_dwordx4 %3, %9, off offset:2048\n\t"              \
               "global_load_dwordx4 %4, %10, off\n\t"                         \
               "global_load_dwordx4 %5, %11, off\n\t"                         \
               "global_load_dwordx4 %6, %12, off\n\t"                         \
               "global_load_dwordx4 %7, %13, off"                             \
               : "=&v"(kpf0), "=&v"(kpf1), "=&v"(kpf2), "=&v"(kpf3),          \
                 "=&v"(vpf0), "=&v"(vpf1), "=&v"(vpf2), "=&v"(vpf3)           \
               : "v"(kb0), "v"(kb0 + 2048), "v"(vb0), "v"(vb0 + 16 * SEQ),    \
                 "v"(vb0 + 32 * SEQ), "v"(vb0 + 48 * SEQ))

#define PF_M()                                                                \
  asm volatile("global_load_dwordx4 %0, %4, off\n\t"                          \
               "global_load_dwordx4 %1, %4, off offset:16\n\t"                \
               "global_load_dwordx4 %2, %4, off offset:64\n\t"                \
               "global_load_dwordx4 %3, %4, off offset:80"                    \
               : "=&v"(mpf0), "=&v"(mpf1), "=&v"(mpf2), "=&v"(mpf3)           \
               : "v"(mpp))

  PF_KV();
  PF_M();

  f32x16 Oacc0 = {}, Oacc1 = {};   // O^T[d][q], dblk 0/1
  float Lacc = 0.0f;
  const int swzA = l31 & 7;

  for (int it = 0; it < 16; ++it) {
    asm volatile("s_waitcnt vmcnt(4)"   // K/V done; 4 mask loads may still fly
                 : "+v"(kpf0), "+v"(kpf1), "+v"(kpf2), "+v"(kpf3),
                   "+v"(vpf0), "+v"(vpf1), "+v"(vpf2), "+v"(vpf3));
    __syncthreads();
    {
      us8_t* kd = (us8_t*)(KldsP + dstOff);
      kd[0] = kpf0; kd[128] = kpf1; kd[256] = kpf2; kd[384] = kpf3;
      us8_t* vd = (us8_t*)(VldsP + dstOff);
      vd[0] = vpf0; vd[128] = vpf1; vd[256] = vpf2; vd[384] = vpf3;
    }
    __syncthreads();

    if (it < 15) {
      kb0 += 4096; vb0 += 64;
      PF_KV();
      asm volatile("s_waitcnt vmcnt(8)"  // drain 4 old mask loads, keep 8 new K/V
                   : "+v"(mpf0), "+v"(mpf1), "+v"(mpf2), "+v"(mpf3));
    } else {
      asm volatile("s_waitcnt vmcnt(0)"
                   : "+v"(mpf0), "+v"(mpf1), "+v"(mpf2), "+v"(mpf3));
    }

    // S-accumulator init = bias + mask (both pre-scaled) as MFMA C-in
    const float* bp = biasF + ((p << 4) + it) * 64 + (hi << 4);
    f32x16 s0, s1;
    initS(s0, bp, mpf0, mpf1);
    initS(s1, bp + 32, mpf2, mpf3);

    if (it < 15) { mpp += 131072; PF_M(); }

    // QK^T: S^T[key][q]
    __builtin_amdgcn_s_setprio(1);
#pragma unroll
    for (int dk = 0; dk < 4; ++dk) {
      const int co = ((dk * 2 + hi) ^ swzA) << 3;
      bf8_t k0 = *(const bf8_t*)(KldsP + l31 * 64 + co);
      bf8_t k1 = *(const bf8_t*)(KldsP + (32 + l31) * 64 + co);
      s0 = __builtin_amdgcn_mfma_f32_32x32x16_bf16(k0, qf[dk], s0, 0, 0, 0);
      s1 = __builtin_amdgcn_mfma_f32_32x32x16_bf16(k1, qf[dk], s1, 0, 0, 0);
    }
    __builtin_amdgcn_s_setprio(0);

    // exp2 + in-register P -> bf16 B-fragments
    bf8_t pfr0, pfr1, pfr2, pfr3;
    packP(s0, Lacc, pfr0, pfr1);
    packP(s1, Lacc, pfr2, pfr3);

    // PV: O^T += V^T * P^T
    __builtin_amdgcn_s_setprio(1);
#pragma unroll
    for (int ks = 0; ks < 4; ++ks) {
      const int co = ((ks * 2 + hi) ^ swzA) << 3;
      bf8_t v0 = *(const bf8_t*)(VldsP + l31 * 64 + co);
      bf8_t v1 = *(const bf8_t*)(VldsP + (32 + l31) * 64 + co);
      bf8_t pp = ks == 0 ? pfr0 : ks == 1 ? pfr1 : ks == 2 ? pfr2 : pfr3;
      Oacc0 = __builtin_amdgcn_mfma_f32_32x32x16_bf16(v0, pp, Oacc0, 0, 0, 0);
      Oacc1 = __builtin_amdgcn_mfma_f32_32x32x16_bf16(v1, pp, Oacc1, 0, 0, 0);
    }
    __builtin_amdgcn_s_setprio(0);
  }
#undef PF_KV
#undef PF_M

  // -------- combine pair partials via LDS (additive: fixed shift, no max) ------
  __syncthreads();   // all K/V/bias LDS reads done; overlay Of[2][64][65] f32
  {
    float* OfP = (float*)smem + p * (64 * 65);
    const int qr = (qw + l31) * 65;
#pragma unroll
    for (int r = 0; r < 16; ++r) {
      int d = (r & 3) + 8 * (r >> 2) + 4 * hi;
      OfP[qr + d] = Oacc0[r];
      OfP[qr + 32 + d] = Oacc1[r];
    }
    float Lf = Lacc + __shfl_xor(Lacc, 32);
    if (hi == 0) OfP[qr + 64] = Lf;
  }
  __syncthreads();
  {
    const float* O0 = (const float*)smem;
    const float* O1 = O0 + 64 * 65;
    const int ql = tid >> 2, dc = tid & 3;
    const int qr = ql * 65;
    float inv = 1.0f / (O0[qr + 64] + O1[qr + 64]);
    unsigned short* orow = attn + ((size_t)b * SEQ + q0 + ql) * E + h * HD + dc * 16;
    us8_t o0, o1;
#pragma unroll
    for (int i = 0; i < 8; ++i)
      o0[i] = f2bf((O0[qr + dc * 16 + i] + O1[qr + dc * 16 + i]) * inv);
#pragma unroll
    for (int i = 0; i < 8; ++i)
      o1[i] = f2bf((O0[qr + dc * 16 + 8 + i] + O1[qr + dc * 16 + 8 + i]) * inv);
    *(us8_t*)orow = o0;
    *(us8_t*)(orow + 8) = o1;
  }
}

// ---------------- output projection GEMM: double-buffered LDS (unchanged) -----
__global__ __launch_bounds__(256) void gemm_out(
    const unsigned short* __restrict__ A, const unsigned short* __restrict__ Bw,
    const float* __restrict__ bo, float* __restrict__ out) {
  __shared__ unsigned short Alds[2][64 * 64];
  __shared__ unsigned short Blds[2][64 * 64];
  const int w = threadIdx.x >> 6, lane = threadIdx.x & 63;
  const int quad = lane >> 4, l15 = lane & 15;
  const int rowBase = blockIdx.x * 64;
  const int colBase = blockIdx.y * 64;
  const int wr = (w & 1) * 32, wc = (w >> 1) * 32;
  f4_t acc[2][2] = {};
  const int swz = l15 & 7;

#define STAGE_OUT(BUF, K0)                                                       \
  {                                                                              \
    const int kk0_ = (K0);                                                       \
    for (int c = 0; c < 2; ++c) {                                                \
      int s = c * 256 + w * 64 + lane;                                           \
      int r = s >> 3, col = ((s & 7) ^ (r & 7)) * 8;                             \
      const unsigned short* ga = A + (size_t)(rowBase + r) * E + kk0_ + col;     \
      __builtin_amdgcn_global_load_lds(                                          \
          (const __attribute__((address_space(1))) void*)ga,                     \
          (__attribute__((address_space(3))) void*)&Alds[BUF][c * 2048 + w * 512], 16, 0, 0); \
      const unsigned short* gb = Bw + (size_t)(colBase + r) * E + kk0_ + col;    \
      __builtin_amdgcn_global_load_lds(                                          \
          (const __attribute__((address_space(1))) void*)gb,                     \
          (__attribute__((address_space(3))) void*)&Blds[BUF][c * 2048 + w * 512], 16, 0, 0); \
    }                                                                            \
  }

  STAGE_OUT(0, 0);
  __builtin_amdgcn_s_waitcnt(0);
  __syncthreads();
  for (int t = 0; t < 12; ++t) {
    const int cur = t & 1;
    if (t < 11) STAGE_OUT(cur ^ 1, (t + 1) * 64);
    bf8_t af[2][2], bfr[2][2];
#pragma unroll
    for (int mi = 0; mi < 2; ++mi)
#pragma unroll
      for (int ks = 0; ks < 2; ++ks)
        af[mi][ks] = *(const bf8_t*)&Alds[cur][(wr + mi * 16 + l15) * 64 + (((ks * 4 + quad) ^ swz) << 3)];
#pragma unroll
    for (int ni = 0; ni < 2; ++ni)
#pragma unroll
      for (int ks = 0; ks < 2; ++ks)
        bfr[ni][ks] = *(const bf8_t*)&Blds[cur][(wc + ni * 16 + l15) * 64 + (((ks * 4 + quad) ^ swz) << 3)];
#pragma unroll
    for (int ks = 0; ks < 2; ++ks)
#pragma unroll
      for (int mi = 0; mi < 2; ++mi)
#pragma unroll
        for (int ni = 0; ni < 2; ++ni)
          acc[mi][ni] = __builtin_amdgcn_mfma_f32_16x16x32_bf16(af[mi][ks], bfr[ni][ks], acc[mi][ni], 0, 0, 0);
    __builtin_amdgcn_s_waitcnt(0);
    __syncthreads();
  }
#undef STAGE_OUT

#pragma unroll
  for (int mi = 0; mi < 2; ++mi) {
#pragma unroll
    for (int ni = 0; ni < 2; ++ni) {
      int gn = colBase + wc + ni * 16 + l15;
      float bias = bo[gn];
#pragma unroll
      for (int r = 0; r < 4; ++r) {
        int gm = rowBase + wr + mi * 16 + quad * 4 + r;
        out[(size_t)gm * E + gn] = acc[mi][ni][r] + bias;
      }
    }
  }
}

extern "C" void kernel_launch(void* const* d_in, const int* in_sizes, int n_in,
                              void* d_out, int out_size, void* d_ws, size_t ws_size,
                              hipStream_t stream) {
  const float* hidden = (const float*)d_in[0];
  const float* mask = (const float*)d_in[1];
  const float* abias = (const float*)d_in[2];
  const float* Wq = (const float*)d_in[3];
  const float* bq = (const float*)d_in[4];
  const float* Wk = (const float*)d_in[5];
  const float* bk = (const float*)d_in[6];
  const float* Wv = (const float*)d_in[7];
  const float* bv = (const float*)d_in[8];
  const float* Wo = (const float*)d_in[9];
  const float* bo = (const float*)d_in[10];
  const float* beta = (const float*)d_in[11];
  const float* betaBias = (const float*)d_in[12];
  float* out = (float*)d_out;

  char* ws = (char*)d_ws;
  unsigned short* Xbf = (unsigned short*)(ws);
  unsigned short* Wqkv = (unsigned short*)(ws + 6291456);
  unsigned short* Wobf = (unsigned short*)(ws + 9830400);
  unsigned short* Qbuf = (unsigned short*)(ws + 11010048);
  unsigned short* Kbuf = (unsigned short*)(ws + 17301504);
  unsigned short* Vtb = (unsigned short*)(ws + 23592960);
  unsigned short* Maskbf = (unsigned short*)(ws + 29884416);  // 16.78 MB
  float* BiasP = (float*)(ws + 46661632);   // 24*2048*4 = 192 KB
  unsigned short* Attn = Xbf;  // Xbf dead after gemm_qkv

  cvt_all<<<6808, 256, 0, stream>>>(hidden, Wq, Wk, Wv, Wo, mask, abias, beta, betaBias,
                                    Xbf, Wqkv, Wobf, Maskbf, BiasP);
  gemm_qkv<<<dim3(64, 18), 256, 0, stream>>>(Xbf, Wqkv, bq, bk, bv, Qbuf, Kbuf, Vtb);
  flash_attn15<<<768, 256, 0, stream>>>(Qbuf, Kbuf, Vtb, Maskbf, BiasP, Attn);
  gemm_out<<<dim3(64, 12), 256, 0, stream>>>(Attn, Wobf, bo, out);
}

// Round 7
// 196.223 us; speedup vs baseline: 1.2508x; 1.0231x over previous
//
#include <hip/hip_runtime.h>
#include <hip/hip_bf16.h>

#define E 768
#define HD 64
#define NH 12
#define BSZ 2
#define SEQ 2048
#define M_ROWS (BSZ * SEQ)   // 4096
#define BH (BSZ * NH)        // 24

#define LOG2E 1.44269504f
#define QSCALE 0.18033688f   // 0.125 * log2e folded into Q
#define MSHIFT 16.0f         // fixed exponent shift (folded into biasP)

typedef float f4_t __attribute__((ext_vector_type(4)));
typedef float f32x16 __attribute__((ext_vector_type(16)));
typedef __bf16 bf8_t __attribute__((ext_vector_type(8)));
typedef unsigned short us8_t __attribute__((ext_vector_type(8)));
typedef unsigned short us4_t __attribute__((ext_vector_type(4)));

__device__ inline unsigned short f2bf(float f) {
  union { float f; unsigned u; } v; v.f = f;
  unsigned u = v.u + 0x7FFFu + ((v.u >> 16) & 1u);
  return (unsigned short)(u >> 16);
}

__device__ inline float ex2(float x) { return __builtin_amdgcn_exp2f(x); }

// bf16 pair -> fp32 (low / high halves of a uint)
__device__ inline float bflo(unsigned u) { union { unsigned u; float f; } v; v.u = u << 16; return v.f; }
__device__ inline float bfhi(unsigned u) { union { unsigned u; float f; } v; v.u = u & 0xFFFF0000u; return v.f; }

// pack two fp32 -> two bf16 in one v_perm (round-half-up) — R1-proven
__device__ inline unsigned pk2(float a, float b) {
  union { float f; unsigned u; } ua, ub;
  ua.f = a; ub.f = b;
  return __builtin_amdgcn_perm(ub.u + 0x8000u, ua.u + 0x8000u, 0x07060302u);
}

// swap a.lanes[32:63] <-> b.lanes[0:31] — R1-proven
__device__ inline void swap32(unsigned& a, unsigned& b) {
  asm volatile("v_permlane32_swap_b32 %0, %1" : "+v"(a), "+v"(b));
}

// ---------------- fused fp32 -> bf16 convert: X, weights, MASK (perm), BIAS (perm)
// blocks: [0,1536) X | [1536,2688) weights | [2688,6784) mask | [6784,6808) bias
// permuted 32x32 MFMA C order: key kk -> idx = (kk>>5)*32 + ((kk>>2)&1)*16
//                                            + ((kk&31)>>3)*4 + (kk&3)
// mask layout:  [b][tile(32)][q(2048)][64] bf16, value = LOG2E*mask
// bias layout:  [bh][tile(32)][64] f32, value = LOG2E*(beta*bias + beta_bias) - MSHIFT
__global__ __launch_bounds__(256) void cvt_all(
    const float* __restrict__ X, const float* __restrict__ Wq,
    const float* __restrict__ Wk, const float* __restrict__ Wv,
    const float* __restrict__ Wo, const float* __restrict__ mask,
    const float* __restrict__ abias, const float* __restrict__ betaP,
    const float* __restrict__ bbiasP,
    unsigned short* __restrict__ Xbf, unsigned short* __restrict__ Wqkv,
    unsigned short* __restrict__ Wobf, unsigned short* __restrict__ maskbf,
    float* __restrict__ biasPf) {
  const int nW = E * E;  // 589824
  int id = blockIdx.x;
  if (id < 2688) {
    const float* src;
    unsigned short* dst;
    float scale = 1.0f;
    int base;
    if (id < 1536) {
      src = X; dst = Xbf; base = id * 2048;
    } else {
      int r = id - 1536;
      int k = r / 288;
      int rb = r - k * 288;
      base = rb * 2048;
      if (k == 0)      { src = Wq; dst = Wqkv;          scale = QSCALE; }
      else if (k == 1) { src = Wk; dst = Wqkv + nW;     }
      else if (k == 2) { src = Wv; dst = Wqkv + 2 * nW; }
      else             { src = Wo; dst = Wobf;          }
    }
    int i = base + threadIdx.x * 8;
    const float4* s = (const float4*)(src + i);
    float4 a = s[0], b = s[1];
    us8_t o;
    o[0] = f2bf(a.x * scale); o[1] = f2bf(a.y * scale);
    o[2] = f2bf(a.z * scale); o[3] = f2bf(a.w * scale);
    o[4] = f2bf(b.x * scale); o[5] = f2bf(b.y * scale);
    o[6] = f2bf(b.z * scale); o[7] = f2bf(b.w * scale);
    *(us8_t*)(dst + i) = o;
    return;
  }
  if (id < 6784) {
    // mask: one (b,q) row per block, 2048 s each, permuted + *LOG2E
    int rowid = id - 2688;             // b*2048 + q
    int bb = rowid >> 11, q = rowid & 2047;
    int s0 = threadIdx.x * 8;
    const float4* s = (const float4*)(mask + (size_t)rowid * 2048 + s0);
    float4 a = s[0], c = s[1];
    int tile = s0 >> 6, kk = s0 & 63;
    int base = ((bb * 32 + tile) * 2048 + q) * 64 + (kk >> 5) * 32 + ((kk & 31) >> 3) * 4;
    us4_t lo, hi4;
    lo[0] = f2bf(a.x * LOG2E); lo[1] = f2bf(a.y * LOG2E);
    lo[2] = f2bf(a.z * LOG2E); lo[3] = f2bf(a.w * LOG2E);
    hi4[0] = f2bf(c.x * LOG2E); hi4[1] = f2bf(c.y * LOG2E);
    hi4[2] = f2bf(c.z * LOG2E); hi4[3] = f2bf(c.w * LOG2E);
    *(us4_t*)(maskbf + base) = lo;        // ((kk>>2)&1)==0 half
    *(us4_t*)(maskbf + base + 16) = hi4;  // ((kk>>2)&1)==1 half
    return;
  }
  {
    // bias: one bh row per block, permuted f32
    int bh = id - 6784;
    int s0 = threadIdx.x * 8;
    const float4* s = (const float4*)(abias + (size_t)bh * 2048 + s0);
    float4 a = s[0], c = s[1];
    float bv = LOG2E * betaP[0];
    float bc = LOG2E * bbiasP[0] - MSHIFT;
    int tile = s0 >> 6, kk = s0 & 63;
    int base = bh * 2048 + tile * 64 + (kk >> 5) * 32 + ((kk & 31) >> 3) * 4;
    f4_t lo = {fmaf(bv, a.x, bc), fmaf(bv, a.y, bc), fmaf(bv, a.z, bc), fmaf(bv, a.w, bc)};
    f4_t hi4 = {fmaf(bv, c.x, bc), fmaf(bv, c.y, bc), fmaf(bv, c.z, bc), fmaf(bv, c.w, bc)};
    *(f4_t*)(biasPf + base) = lo;
    *(f4_t*)(biasPf + base + 16) = hi4;
  }
}

// ---------------- fused QKV GEMM: 128x128 tile, BK=64, m97-style single-buffer -
// 4 waves (2x2), each 64x64 output; 32 MFMA + 16 ds_read_b128 per iter (2:1 vs
// the old 64x128's 1:1). Grid (32,18): halves staged bytes vs 64x128.
__global__ __launch_bounds__(256, 3) void gemm_qkv(
    const unsigned short* __restrict__ A, const unsigned short* __restrict__ Bw,
    const float* __restrict__ bq, const float* __restrict__ bk, const float* __restrict__ bv,
    unsigned short* __restrict__ Qb, unsigned short* __restrict__ Kb,
    unsigned short* __restrict__ Vtb) {
  __shared__ unsigned short Alds[128 * 64];   // 16 KB
  __shared__ unsigned short Blds[128 * 64];   // 16 KB
  const int w = threadIdx.x >> 6, lane = threadIdx.x & 63;
  const int quad = lane >> 4, l15 = lane & 15;
  const int rowBase = blockIdx.x * 128;
  const int colBase = blockIdx.y * 128;
  const int wr = (w & 1) * 64, wc = (w >> 1) * 64;
  f4_t acc[4][4] = {};
  const int swz = l15 & 7;

  for (int k0 = 0; k0 < E; k0 += 64) {
    __syncthreads();
    // A,B: 1024 chunks each (128 rows x 8), 4 per thread
#pragma unroll
    for (int c = 0; c < 4; ++c) {
      int s = c * 256 + w * 64 + lane;
      int r = s >> 3, col = ((s & 7) ^ (r & 7)) * 8;
      const unsigned short* ga = A + (size_t)(rowBase + r) * E + k0 + col;
      __builtin_amdgcn_global_load_lds((const __attribute__((address_space(1))) void*)ga,
          (__attribute__((address_space(3))) void*)&Alds[c * 2048 + w * 512], 16, 0, 0);
      const unsigned short* gb = Bw + (size_t)(colBase + r) * E + k0 + col;
      __builtin_amdgcn_global_load_lds((const __attribute__((address_space(1))) void*)gb,
          (__attribute__((address_space(3))) void*)&Blds[c * 2048 + w * 512], 16, 0, 0);
    }
    __builtin_amdgcn_s_waitcnt(0);
    __syncthreads();
    bf8_t af[4][2], bfr[4][2];
#pragma unroll
    for (int mi = 0; mi < 4; ++mi)
#pragma unroll
      for (int ks = 0; ks < 2; ++ks)
        af[mi][ks] = *(const bf8_t*)&Alds[(wr + mi * 16 + l15) * 64 + (((ks * 4 + quad) ^ swz) << 3)];
#pragma unroll
    for (int ni = 0; ni < 4; ++ni)
#pragma unroll
      for (int ks = 0; ks < 2; ++ks)
        bfr[ni][ks] = *(const bf8_t*)&Blds[(wc + ni * 16 + l15) * 64 + (((ks * 4 + quad) ^ swz) << 3)];
#pragma unroll
    for (int ks = 0; ks < 2; ++ks)
#pragma unroll
      for (int mi = 0; mi < 4; ++mi)
#pragma unroll
        for (int ni = 0; ni < 4; ++ni)
          acc[mi][ni] = __builtin_amdgcn_mfma_f32_16x16x32_bf16(af[mi][ks], bfr[ni][ks], acc[mi][ni], 0, 0, 0);
  }

  const int which = blockIdx.y / 6;            // 0=Q 1=K 2=V
  const int colMat = colBase - which * E;      // 0..640
  __syncthreads();   // all LDS frag reads done; Blds reusable as scratch
  if (which < 2) {
    const float* biasP = (which == 0) ? bq : bk;
    unsigned short* dst = (which == 0) ? Qb : Kb;
    const float bscale = (which == 0) ? QSCALE : 1.0f;
    const int cnBase = colMat + wc;            // multiple of 64 -> single head
    const int h = cnBase >> 6;
    float biasv[4];
#pragma unroll
    for (int ni = 0; ni < 4; ++ni) biasv[ni] = biasP[cnBase + ni * 16 + l15] * bscale;
    unsigned short* T = Blds + w * 1024;       // per-wave 16x64 scratch
    const int row = lane >> 2, colE = (lane & 3) * 16;
#pragma unroll
    for (int mi = 0; mi < 4; ++mi) {
#pragma unroll
      for (int ni = 0; ni < 4; ++ni)
#pragma unroll
        for (int r = 0; r < 4; ++r)
          T[(quad * 4 + r) * 64 + ni * 16 + l15] = f2bf(acc[mi][ni][r] + biasv[ni]);
      us8_t o0 = *(const us8_t*)&T[row * 64 + colE];
      us8_t o1 = *(const us8_t*)&T[row * 64 + colE + 8];
      int gm = rowBase + wr + mi * 16 + row;
      int b = gm >> 11, t = gm & 2047;
      unsigned short* drow = dst + ((size_t)(b * NH + h) * SEQ + t) * HD;
      *(us8_t*)&drow[colE] = o0;
      *(us8_t*)&drow[colE + 8] = o1;
    }
  } else {
    // V^T epilogue: [bh][d][t], 4 consecutive t per store
#pragma unroll
    for (int mi = 0; mi < 4; ++mi) {
#pragma unroll
      for (int ni = 0; ni < 4; ++ni) {
        int cn = colMat + wc + ni * 16 + l15;
        int h = cn >> 6, d = cn & 63;
        float bias = bv[cn];
        int gm0 = rowBase + wr + mi * 16 + quad * 4;
        int b = gm0 >> 11, t = gm0 & 2047;
        us4_t o4;
#pragma unroll
        for (int r = 0; r < 4; ++r) o4[r] = f2bf(acc[mi][ni][r] + bias);
        *(us4_t*)&Vtb[((size_t)(b * NH + h) * HD + d) * SEQ + t] = o4;
      }
    }
  }
}

// ---------------- flash attention v16: v15 + tree-reduced L chain -------------
__device__ inline void initS(f32x16& SA, const float* bp, us8_t ma, us8_t mb) {
  union { us8_t s; unsigned u[4]; } ca, cb;
  ca.s = ma; cb.s = mb;
#pragma unroll
  for (int g = 0; g < 4; ++g) {
    f4_t bw = *(const f4_t*)(bp + g * 4);
    unsigned wl = (g < 2) ? ca.u[2 * g] : cb.u[2 * g - 4];
    unsigned wh = (g < 2) ? ca.u[2 * g + 1] : cb.u[2 * g - 3];
    SA[4 * g + 0] = bw[0] + bflo(wl);
    SA[4 * g + 1] = bw[1] + bfhi(wl);
    SA[4 * g + 2] = bw[2] + bflo(wh);
    SA[4 * g + 3] = bw[3] + bfhi(wh);
  }
}

__device__ inline void packP(f32x16& SA, float& L, bf8_t& F0, bf8_t& F1) {
#pragma unroll
  for (int r = 0; r < 16; ++r) SA[r] = ex2(SA[r]);
  // tree-reduce (breaks the 16-long serial dependency chain of L += ...)
  float t0 = (SA[0] + SA[1]) + (SA[2] + SA[3]);
  float t1 = (SA[4] + SA[5]) + (SA[6] + SA[7]);
  float t2 = (SA[8] + SA[9]) + (SA[10] + SA[11]);
  float t3 = (SA[12] + SA[13]) + (SA[14] + SA[15]);
  L += (t0 + t1) + (t2 + t3);
  unsigned u0 = pk2(SA[0], SA[1]), u1 = pk2(SA[2], SA[3]);
  unsigned u2 = pk2(SA[4], SA[5]), u3 = pk2(SA[6], SA[7]);
  unsigned u4 = pk2(SA[8], SA[9]), u5 = pk2(SA[10], SA[11]);
  unsigned u6 = pk2(SA[12], SA[13]), u7 = pk2(SA[14], SA[15]);
  swap32(u0, u2); swap32(u1, u3); swap32(u4, u6); swap32(u5, u7);
  union { unsigned u[4]; bf8_t b; } fa, fb;
  fa.u[0] = u0; fa.u[1] = u1; fa.u[2] = u2; fa.u[3] = u3;
  fb.u[0] = u4; fb.u[1] = u5; fb.u[2] = u6; fb.u[3] = u7;
  F0 = fa.b; F1 = fb.b;
}

__global__ __launch_bounds__(256, 3) void flash_attn16(
    const unsigned short* __restrict__ Qb, const unsigned short* __restrict__ Kb,
    const unsigned short* __restrict__ Vt, const unsigned short* __restrict__ maskP,
    const float* __restrict__ biasPf, unsigned short* __restrict__ attn) {
  __shared__ __align__(16) char smem[40960];
  const int tid = threadIdx.x;
  const int w = tid >> 6, lane = tid & 63;
  const int l31 = lane & 31, hi = lane >> 5;
  const int p = w >> 1, qw = (w & 1) * 32;
  const int id = blockIdx.x;
  const int h = id >> 6;            // 0..11
  const int qb = id & 63;
  const int qt = qb >> 1, b = qb & 1;   // XCD = id%8 = qb%8 -> all 12 h share XCD
  const int bh = b * NH + h;
  const int q0 = qt * 64;
  const int q = q0 + qw + l31;      // this lane's query (column of S^T)

  unsigned short* KldsP = (unsigned short*)(smem + p * 16384);  // [64 key][64 d] swizzled
  unsigned short* VldsP = KldsP + 4096;                         // [64 d][64 key] swizzled
  float* biasF = (float*)(smem + 32768);                        // [2048] permuted f32

  {
    const float* srcB = biasPf + bh * 2048 + tid * 8;
    *(f4_t*)&biasF[tid * 8] = *(const f4_t*)srcB;
    *(f4_t*)&biasF[tid * 8 + 4] = *(const f4_t*)(srcB + 4);
  }

  bf8_t qf[4];
  {
    const unsigned short* qbase = Qb + ((size_t)bh * SEQ + q) * HD + hi * 8;
#pragma unroll
    for (int dk = 0; dk < 4; ++dk) qf[dk] = *(const bf8_t*)(qbase + dk * 16);
  }

  const int li = (w & 1) * 64 + lane;
  const int r0 = li >> 3, cc = li & 7;
  const int dstOff = r0 * 64 + ((cc ^ (r0 & 7)) << 3);
  const unsigned short* kb0 = Kb + (size_t)bh * SEQ * HD + (p * 1024 + r0) * 64 + cc * 8;
  const unsigned short* VtG = Vt + (size_t)bh * HD * SEQ;
  const unsigned short* vb0 = VtG + (size_t)r0 * SEQ + p * 1024 + cc * 8;
  const unsigned short* mpp = maskP + (((size_t)(b * 32 + p * 16) * 2048) + q) * 64 + hi * 16;

  us8_t kpf0, kpf1, kpf2, kpf3, vpf0, vpf1, vpf2, vpf3, mpf0, mpf1, mpf2, mpf3;

#define PF_KV()                                                               \
  asm volatile("global_load_dwordx4 %0, %8, off\n\t"                          \
               "global_load_dwordx4 %1, %8, off offset:2048\n\t"              \
               "global_load_dwordx4 %2, %9, off\n\t"                          \
               "global_load_dwordx4 %3, %9, off offset:2048\n\t"              \
               "global_load_dwordx4 %4, %10, off\n\t"                         \
               "global_load_dwordx4 %5, %11, off\n\t"                         \
               "global_load_dwordx4 %6, %12, off\n\t"                         \
               "global_load_dwordx4 %7, %13, off"                             \
               : "=&v"(kpf0), "=&v"(kpf1), "=&v"(kpf2), "=&v"(kpf3),          \
                 "=&v"(vpf0), "=&v"(vpf1), "=&v"(vpf2), "=&v"(vpf3)           \
               : "v"(kb0), "v"(kb0 + 2048), "v"(vb0), "v"(vb0 + 16 * SEQ),    \
                 "v"(vb0 + 32 * SEQ), "v"(vb0 + 48 * SEQ))

#define PF_M()                                                                \
  asm volatile("global_load_dwordx4 %0, %4, off\n\t"                          \
               "global_load_dwordx4 %1, %4, off offset:16\n\t"                \
               "global_load_dwordx4 %2, %4, off offset:64\n\t"                \
               "global_load_dwordx4 %3, %4, off offset:80"                    \
               : "=&v"(mpf0), "=&v"(mpf1), "=&v"(mpf2), "=&v"(mpf3)           \
               : "v"(mpp))

  PF_KV();
  PF_M();

  f32x16 Oacc0 = {}, Oacc1 = {};   // O^T[d][q], dblk 0/1
  float Lacc = 0.0f;
  const int swzA = l31 & 7;

  for (int it = 0; it < 16; ++it) {
    asm volatile("s_waitcnt vmcnt(4)"   // K/V done; 4 mask loads may still fly
                 : "+v"(kpf0), "+v"(kpf1), "+v"(kpf2), "+v"(kpf3),
                   "+v"(vpf0), "+v"(vpf1), "+v"(vpf2), "+v"(vpf3));
    __syncthreads();
    {
      us8_t* kd = (us8_t*)(KldsP + dstOff);
      kd[0] = kpf0; kd[128] = kpf1; kd[256] = kpf2; kd[384] = kpf3;
      us8_t* vd = (us8_t*)(VldsP + dstOff);
      vd[0] = vpf0; vd[128] = vpf1; vd[256] = vpf2; vd[384] = vpf3;
    }
    __syncthreads();

    if (it < 15) {
      kb0 += 4096; vb0 += 64;
      PF_KV();
      asm volatile("s_waitcnt vmcnt(8)"  // drain 4 old mask loads, keep 8 new K/V
                   : "+v"(mpf0), "+v"(mpf1), "+v"(mpf2), "+v"(mpf3));
    } else {
      asm volatile("s_waitcnt vmcnt(0)"
                   : "+v"(mpf0), "+v"(mpf1), "+v"(mpf2), "+v"(mpf3));
    }

    // S-accumulator init = bias + mask (both pre-scaled) as MFMA C-in
    const float* bp = biasF + ((p << 4) + it) * 64 + (hi << 4);
    f32x16 s0, s1;
    initS(s0, bp, mpf0, mpf1);
    initS(s1, bp + 32, mpf2, mpf3);

    if (it < 15) { mpp += 131072; PF_M(); }

    // QK^T: S^T[key][q]
    __builtin_amdgcn_s_setprio(1);
#pragma unroll
    for (int dk = 0; dk < 4; ++dk) {
      const int co = ((dk * 2 + hi) ^ swzA) << 3;
      bf8_t k0 = *(const bf8_t*)(KldsP + l31 * 64 + co);
      bf8_t k1 = *(const bf8_t*)(KldsP + (32 + l31) * 64 + co);
      s0 = __builtin_amdgcn_mfma_f32_32x32x16_bf16(k0, qf[dk], s0, 0, 0, 0);
      s1 = __builtin_amdgcn_mfma_f32_32x32x16_bf16(k1, qf[dk], s1, 0, 0, 0);
    }
    __builtin_amdgcn_s_setprio(0);

    // exp2 + in-register P -> bf16 B-fragments
    bf8_t pfr0, pfr1, pfr2, pfr3;
    packP(s0, Lacc, pfr0, pfr1);
    packP(s1, Lacc, pfr2, pfr3);

    // PV: O^T += V^T * P^T
    __builtin_amdgcn_s_setprio(1);
#pragma unroll
    for (int ks = 0; ks < 4; ++ks) {
      const int co = ((ks * 2 + hi) ^ swzA) << 3;
      bf8_t v0 = *(const bf8_t*)(VldsP + l31 * 64 + co);
      bf8_t v1 = *(const bf8_t*)(VldsP + (32 + l31) * 64 + co);
      bf8_t pp = ks == 0 ? pfr0 : ks == 1 ? pfr1 : ks == 2 ? pfr2 : pfr3;
      Oacc0 = __builtin_amdgcn_mfma_f32_32x32x16_bf16(v0, pp, Oacc0, 0, 0, 0);
      Oacc1 = __builtin_amdgcn_mfma_f32_32x32x16_bf16(v1, pp, Oacc1, 0, 0, 0);
    }
    __builtin_amdgcn_s_setprio(0);
  }
#undef PF_KV
#undef PF_M

  // -------- combine pair partials via LDS (additive: fixed shift, no max) ------
  __syncthreads();   // all K/V/bias LDS reads done; overlay Of[2][64][65] f32
  {
    float* OfP = (float*)smem + p * (64 * 65);
    const int qr = (qw + l31) * 65;
#pragma unroll
    for (int r = 0; r < 16; ++r) {
      int d = (r & 3) + 8 * (r >> 2) + 4 * hi;
      OfP[qr + d] = Oacc0[r];
      OfP[qr + 32 + d] = Oacc1[r];
    }
    float Lf = Lacc + __shfl_xor(Lacc, 32);
    if (hi == 0) OfP[qr + 64] = Lf;
  }
  __syncthreads();
  {
    const float* O0 = (const float*)smem;
    const float* O1 = O0 + 64 * 65;
    const int ql = tid >> 2, dc = tid & 3;
    const int qr = ql * 65;
    float inv = 1.0f / (O0[qr + 64] + O1[qr + 64]);
    unsigned short* orow = attn + ((size_t)b * SEQ + q0 + ql) * E + h * HD + dc * 16;
    us8_t o0, o1;
#pragma unroll
    for (int i = 0; i < 8; ++i)
      o0[i] = f2bf((O0[qr + dc * 16 + i] + O1[qr + dc * 16 + i]) * inv);
#pragma unroll
    for (int i = 0; i < 8; ++i)
      o1[i] = f2bf((O0[qr + dc * 16 + 8 + i] + O1[qr + dc * 16 + 8 + i]) * inv);
    *(us8_t*)orow = o0;
    *(us8_t*)(orow + 8) = o1;
  }
}

// ---------------- output projection GEMM: 64x128 tile, single-buffer ----------
__global__ __launch_bounds__(256) void gemm_out(
    const unsigned short* __restrict__ A, const unsigned short* __restrict__ Bw,
    const float* __restrict__ bo, float* __restrict__ out) {
  __shared__ unsigned short Alds[64 * 64];    // 8 KB
  __shared__ unsigned short Blds[128 * 64];   // 16 KB
  const int w = threadIdx.x >> 6, lane = threadIdx.x & 63;
  const int quad = lane >> 4, l15 = lane & 15;
  const int rowBase = blockIdx.x * 64;
  const int colBase = blockIdx.y * 128;
  const int wr = (w & 1) * 32, wc = (w >> 1) * 64;
  f4_t acc[2][4] = {};
  const int swz = l15 & 7;

  for (int k0 = 0; k0 < E; k0 += 64) {
    __syncthreads();
#pragma unroll
    for (int c = 0; c < 2; ++c) {
      int s = c * 256 + w * 64 + lane;
      int r = s >> 3, col = ((s & 7) ^ (r & 7)) * 8;
      const unsigned short* ga = A + (size_t)(rowBase + r) * E + k0 + col;
      __builtin_amdgcn_global_load_lds((const __attribute__((address_space(1))) void*)ga,
          (__attribute__((address_space(3))) void*)&Alds[c * 2048 + w * 512], 16, 0, 0);
    }
#pragma unroll
    for (int c = 0; c < 4; ++c) {
      int s = c * 256 + w * 64 + lane;
      int r = s >> 3, col = ((s & 7) ^ (r & 7)) * 8;
      const unsigned short* gb = Bw + (size_t)(colBase + r) * E + k0 + col;
      __builtin_amdgcn_global_load_lds((const __attribute__((address_space(1))) void*)gb,
          (__attribute__((address_space(3))) void*)&Blds[c * 2048 + w * 512], 16, 0, 0);
    }
    __builtin_amdgcn_s_waitcnt(0);
    __syncthreads();
    bf8_t af[2][2], bfr[4][2];
#pragma unroll
    for (int mi = 0; mi < 2; ++mi)
#pragma unroll
      for (int ks = 0; ks < 2; ++ks)
        af[mi][ks] = *(const bf8_t*)&Alds[(wr + mi * 16 + l15) * 64 + (((ks * 4 + quad) ^ swz) << 3)];
#pragma unroll
    for (int ni = 0; ni < 4; ++ni)
#pragma unroll
      for (int ks = 0; ks < 2; ++ks)
        bfr[ni][ks] = *(const bf8_t*)&Blds[(wc + ni * 16 + l15) * 64 + (((ks * 4 + quad) ^ swz) << 3)];
#pragma unroll
    for (int ks = 0; ks < 2; ++ks)
#pragma unroll
      for (int mi = 0; mi < 2; ++mi)
#pragma unroll
        for (int ni = 0; ni < 4; ++ni)
          acc[mi][ni] = __builtin_amdgcn_mfma_f32_16x16x32_bf16(af[mi][ks], bfr[ni][ks], acc[mi][ni], 0, 0, 0);
  }

#pragma unroll
  for (int mi = 0; mi < 2; ++mi) {
#pragma unroll
    for (int ni = 0; ni < 4; ++ni) {
      int gn = colBase + wc + ni * 16 + l15;
      float bias = bo[gn];
#pragma unroll
      for (int r = 0; r < 4; ++r) {
        int gm = rowBase + wr + mi * 16 + quad * 4 + r;
        out[(size_t)gm * E + gn] = acc[mi][ni][r] + bias;
      }
    }
  }
}

extern "C" void kernel_launch(void* const* d_in, const int* in_sizes, int n_in,
                              void* d_out, int out_size, void* d_ws, size_t ws_size,
                              hipStream_t stream) {
  const float* hidden = (const float*)d_in[0];
  const float* mask = (const float*)d_in[1];
  const float* abias = (const float*)d_in[2];
  const float* Wq = (const float*)d_in[3];
  const float* bq = (const float*)d_in[4];
  const float* Wk = (const float*)d_in[5];
  const float* bk = (const float*)d_in[6];
  const float* Wv = (const float*)d_in[7];
  const float* bv = (const float*)d_in[8];
  const float* Wo = (const float*)d_in[9];
  const float* bo = (const float*)d_in[10];
  const float* beta = (const float*)d_in[11];
  const float* betaBias = (const float*)d_in[12];
  float* out = (float*)d_out;

  char* ws = (char*)d_ws;
  unsigned short* Xbf = (unsigned short*)(ws);
  unsigned short* Wqkv = (unsigned short*)(ws + 6291456);
  unsigned short* Wobf = (unsigned short*)(ws + 9830400);
  unsigned short* Qbuf = (unsigned short*)(ws + 11010048);
  unsigned short* Kbuf = (unsigned short*)(ws + 17301504);
  unsigned short* Vtb = (unsigned short*)(ws + 23592960);
  unsigned short* Maskbf = (unsigned short*)(ws + 29884416);  // 16.78 MB
  float* BiasP = (float*)(ws + 46661632);   // 24*2048*4 = 192 KB
  unsigned short* Attn = Xbf;  // Xbf dead after gemm_qkv

  cvt_all<<<6808, 256, 0, stream>>>(hidden, Wq, Wk, Wv, Wo, mask, abias, beta, betaBias,
                                    Xbf, Wqkv, Wobf, Maskbf, BiasP);
  gemm_qkv<<<dim3(32, 18), 256, 0, stream>>>(Xbf, Wqkv, bq, bk, bv, Qbuf, Kbuf, Vtb);
  flash_attn16<<<768, 256, 0, stream>>>(Qbuf, Kbuf, Vtb, Maskbf, BiasP, Attn);
  gemm_out<<<dim3(64, 6), 256, 0, stream>>>(Attn, Wobf, bo, out);
}

// Round 10
// 191.121 us; speedup vs baseline: 1.2842x; 1.0267x over previous
//
#include <hip/hip_runtime.h>
#include <hip/hip_bf16.h>

#define E 768
#define HD 64
#define NH 12
#define BSZ 2
#define SEQ 2048
#define M_ROWS (BSZ * SEQ)   // 4096
#define BH (BSZ * NH)        // 24

#define LOG2E 1.44269504f
#define QSCALE 0.18033688f   // 0.125 * log2e folded into Q
#define MSHIFT 16.0f         // fixed exponent shift (folded into biasP)

typedef float f4_t __attribute__((ext_vector_type(4)));
typedef float f32x16 __attribute__((ext_vector_type(16)));
typedef __bf16 bf8_t __attribute__((ext_vector_type(8)));
typedef unsigned short us8_t __attribute__((ext_vector_type(8)));
typedef unsigned short us4_t __attribute__((ext_vector_type(4)));

__device__ inline unsigned short f2bf(float f) {
  union { float f; unsigned u; } v; v.f = f;
  unsigned u = v.u + 0x7FFFu + ((v.u >> 16) & 1u);
  return (unsigned short)(u >> 16);
}

__device__ inline float ex2(float x) { return __builtin_amdgcn_exp2f(x); }

// bf16 pair -> fp32 (low / high halves of a uint)
__device__ inline float bflo(unsigned u) { union { unsigned u; float f; } v; v.u = u << 16; return v.f; }
__device__ inline float bfhi(unsigned u) { union { unsigned u; float f; } v; v.u = u & 0xFFFF0000u; return v.f; }

// pack two fp32 -> two bf16 in one v_perm (round-half-up) — R1-proven
__device__ inline unsigned pk2(float a, float b) {
  union { float f; unsigned u; } ua, ub;
  ua.f = a; ub.f = b;
  return __builtin_amdgcn_perm(ub.u + 0x8000u, ua.u + 0x8000u, 0x07060302u);
}

// swap a.lanes[32:63] <-> b.lanes[0:31] — R1-proven
__device__ inline void swap32(unsigned& a, unsigned& b) {
  asm volatile("v_permlane32_swap_b32 %0, %1" : "+v"(a), "+v"(b));
}

// ---------------- fused fp32 -> bf16 convert: X, weights, MASK (perm), BIAS (perm)
// blocks: [0,1536) X | [1536,2688) weights | [2688,6784) mask | [6784,6808) bias
// permuted 32x32 MFMA C order: key kk -> idx = (kk>>5)*32 + ((kk>>2)&1)*16
//                                            + ((kk&31)>>3)*4 + (kk&3)
// mask layout:  [b][tile(32)][q(2048)][64] bf16, value = LOG2E*mask
// bias layout:  [bh][tile(32)][64] f32, value = LOG2E*(beta*bias + beta_bias) - MSHIFT
__global__ __launch_bounds__(256) void cvt_all(
    const float* __restrict__ X, const float* __restrict__ Wq,
    const float* __restrict__ Wk, const float* __restrict__ Wv,
    const float* __restrict__ Wo, const float* __restrict__ mask,
    const float* __restrict__ abias, const float* __restrict__ betaP,
    const float* __restrict__ bbiasP,
    unsigned short* __restrict__ Xbf, unsigned short* __restrict__ Wqkv,
    unsigned short* __restrict__ Wobf, unsigned short* __restrict__ maskbf,
    float* __restrict__ biasPf) {
  const int nW = E * E;  // 589824
  int id = blockIdx.x;
  if (id < 2688) {
    const float* src;
    unsigned short* dst;
    float scale = 1.0f;
    int base;
    if (id < 1536) {
      src = X; dst = Xbf; base = id * 2048;
    } else {
      int r = id - 1536;
      int k = r / 288;
      int rb = r - k * 288;
      base = rb * 2048;
      if (k == 0)      { src = Wq; dst = Wqkv;          scale = QSCALE; }
      else if (k == 1) { src = Wk; dst = Wqkv + nW;     }
      else if (k == 2) { src = Wv; dst = Wqkv + 2 * nW; }
      else             { src = Wo; dst = Wobf;          }
    }
    int i = base + threadIdx.x * 8;
    const float4* s = (const float4*)(src + i);
    float4 a = s[0], b = s[1];
    us8_t o;
    o[0] = f2bf(a.x * scale); o[1] = f2bf(a.y * scale);
    o[2] = f2bf(a.z * scale); o[3] = f2bf(a.w * scale);
    o[4] = f2bf(b.x * scale); o[5] = f2bf(b.y * scale);
    o[6] = f2bf(b.z * scale); o[7] = f2bf(b.w * scale);
    *(us8_t*)(dst + i) = o;
    return;
  }
  if (id < 6784) {
    // mask: one (b,q) row per block, 2048 s each, permuted + *LOG2E
    int rowid = id - 2688;             // b*2048 + q
    int bb = rowid >> 11, q = rowid & 2047;
    int s0 = threadIdx.x * 8;
    const float4* s = (const float4*)(mask + (size_t)rowid * 2048 + s0);
    float4 a = s[0], c = s[1];
    int tile = s0 >> 6, kk = s0 & 63;
    int base = ((bb * 32 + tile) * 2048 + q) * 64 + (kk >> 5) * 32 + ((kk & 31) >> 3) * 4;
    us4_t lo, hi4;
    lo[0] = f2bf(a.x * LOG2E); lo[1] = f2bf(a.y * LOG2E);
    lo[2] = f2bf(a.z * LOG2E); lo[3] = f2bf(a.w * LOG2E);
    hi4[0] = f2bf(c.x * LOG2E); hi4[1] = f2bf(c.y * LOG2E);
    hi4[2] = f2bf(c.z * LOG2E); hi4[3] = f2bf(c.w * LOG2E);
    *(us4_t*)(maskbf + base) = lo;        // ((kk>>2)&1)==0 half
    *(us4_t*)(maskbf + base + 16) = hi4;  // ((kk>>2)&1)==1 half
    return;
  }
  {
    // bias: one bh row per block, permuted f32
    int bh = id - 6784;
    int s0 = threadIdx.x * 8;
    const float4* s = (const float4*)(abias + (size_t)bh * 2048 + s0);
    float4 a = s[0], c = s[1];
    float bv = LOG2E * betaP[0];
    float bc = LOG2E * bbiasP[0] - MSHIFT;
    int tile = s0 >> 6, kk = s0 & 63;
    int base = bh * 2048 + tile * 64 + (kk >> 5) * 32 + ((kk & 31) >> 3) * 4;
    f4_t lo = {fmaf(bv, a.x, bc), fmaf(bv, a.y, bc), fmaf(bv, a.z, bc), fmaf(bv, a.w, bc)};
    f4_t hi4 = {fmaf(bv, c.x, bc), fmaf(bv, c.y, bc), fmaf(bv, c.z, bc), fmaf(bv, c.w, bc)};
    *(f4_t*)(biasPf + base) = lo;
    *(f4_t*)(biasPf + base + 16) = hi4;
  }
}

// ---------------- fused QKV GEMM: 128x128 tile, BK=64 (unchanged from R7) -----
__global__ __launch_bounds__(256, 3) void gemm_qkv(
    const unsigned short* __restrict__ A, const unsigned short* __restrict__ Bw,
    const float* __restrict__ bq, const float* __restrict__ bk, const float* __restrict__ bv,
    unsigned short* __restrict__ Qb, unsigned short* __restrict__ Kb,
    unsigned short* __restrict__ Vtb) {
  __shared__ unsigned short Alds[128 * 64];   // 16 KB
  __shared__ unsigned short Blds[128 * 64];   // 16 KB
  const int w = threadIdx.x >> 6, lane = threadIdx.x & 63;
  const int quad = lane >> 4, l15 = lane & 15;
  const int rowBase = blockIdx.x * 128;
  const int colBase = blockIdx.y * 128;
  const int wr = (w & 1) * 64, wc = (w >> 1) * 64;
  f4_t acc[4][4] = {};
  const int swz = l15 & 7;

  for (int k0 = 0; k0 < E; k0 += 64) {
    __syncthreads();
#pragma unroll
    for (int c = 0; c < 4; ++c) {
      int s = c * 256 + w * 64 + lane;
      int r = s >> 3, col = ((s & 7) ^ (r & 7)) * 8;
      const unsigned short* ga = A + (size_t)(rowBase + r) * E + k0 + col;
      __builtin_amdgcn_global_load_lds((const __attribute__((address_space(1))) void*)ga,
          (__attribute__((address_space(3))) void*)&Alds[c * 2048 + w * 512], 16, 0, 0);
      const unsigned short* gb = Bw + (size_t)(colBase + r) * E + k0 + col;
      __builtin_amdgcn_global_load_lds((const __attribute__((address_space(1))) void*)gb,
          (__attribute__((address_space(3))) void*)&Blds[c * 2048 + w * 512], 16, 0, 0);
    }
    __builtin_amdgcn_s_waitcnt(0);
    __syncthreads();
    bf8_t af[4][2], bfr[4][2];
#pragma unroll
    for (int mi = 0; mi < 4; ++mi)
#pragma unroll
      for (int ks = 0; ks < 2; ++ks)
        af[mi][ks] = *(const bf8_t*)&Alds[(wr + mi * 16 + l15) * 64 + (((ks * 4 + quad) ^ swz) << 3)];
#pragma unroll
    for (int ni = 0; ni < 4; ++ni)
#pragma unroll
      for (int ks = 0; ks < 2; ++ks)
        bfr[ni][ks] = *(const bf8_t*)&Blds[(wc + ni * 16 + l15) * 64 + (((ks * 4 + quad) ^ swz) << 3)];
#pragma unroll
    for (int ks = 0; ks < 2; ++ks)
#pragma unroll
      for (int mi = 0; mi < 4; ++mi)
#pragma unroll
        for (int ni = 0; ni < 4; ++ni)
          acc[mi][ni] = __builtin_amdgcn_mfma_f32_16x16x32_bf16(af[mi][ks], bfr[ni][ks], acc[mi][ni], 0, 0, 0);
  }

  const int which = blockIdx.y / 6;            // 0=Q 1=K 2=V
  const int colMat = colBase - which * E;      // 0..640
  __syncthreads();   // all LDS frag reads done; Blds reusable as scratch
  if (which < 2) {
    const float* biasP = (which == 0) ? bq : bk;
    unsigned short* dst = (which == 0) ? Qb : Kb;
    const float bscale = (which == 0) ? QSCALE : 1.0f;
    const int cnBase = colMat + wc;            // multiple of 64 -> single head
    const int h = cnBase >> 6;
    float biasv[4];
#pragma unroll
    for (int ni = 0; ni < 4; ++ni) biasv[ni] = biasP[cnBase + ni * 16 + l15] * bscale;
    unsigned short* T = Blds + w * 1024;       // per-wave 16x64 scratch
    const int row = lane >> 2, colE = (lane & 3) * 16;
#pragma unroll
    for (int mi = 0; mi < 4; ++mi) {
#pragma unroll
      for (int ni = 0; ni < 4; ++ni)
#pragma unroll
        for (int r = 0; r < 4; ++r)
          T[(quad * 4 + r) * 64 + ni * 16 + l15] = f2bf(acc[mi][ni][r] + biasv[ni]);
      us8_t o0 = *(const us8_t*)&T[row * 64 + colE];
      us8_t o1 = *(const us8_t*)&T[row * 64 + colE + 8];
      int gm = rowBase + wr + mi * 16 + row;
      int b = gm >> 11, t = gm & 2047;
      unsigned short* drow = dst + ((size_t)(b * NH + h) * SEQ + t) * HD;
      *(us8_t*)&drow[colE] = o0;
      *(us8_t*)&drow[colE + 8] = o1;
    }
  } else {
    // V^T epilogue: [bh][d][t], 4 consecutive t per store
#pragma unroll
    for (int mi = 0; mi < 4; ++mi) {
#pragma unroll
      for (int ni = 0; ni < 4; ++ni) {
        int cn = colMat + wc + ni * 16 + l15;
        int h = cn >> 6, d = cn & 63;
        float bias = bv[cn];
        int gm0 = rowBase + wr + mi * 16 + quad * 4;
        int b = gm0 >> 11, t = gm0 & 2047;
        us4_t o4;
#pragma unroll
        for (int r = 0; r < 4; ++r) o4[r] = f2bf(acc[mi][ni][r] + bias);
        *(us4_t*)&Vtb[((size_t)(b * NH + h) * HD + d) * SEQ + t] = o4;
      }
    }
  }
}

// ---------------- flash attention v17b: raw barrier via builtin ----------------
// __syncthreads() emits s_waitcnt vmcnt(0) lgkmcnt(0) before s_barrier -> every
// iteration force-drained all 12 prefetch loads, nullifying the counted-vmcnt
// scheme (T4). Fix: __builtin_amdgcn_s_barrier() (the m201-verified form) with
// explicit asm waitcnts: lgkmcnt(0) after the K/V ds_writes before barrier2.
__device__ inline void initS(f32x16& SA, const float* bp, us8_t ma, us8_t mb) {
  union { us8_t s; unsigned u[4]; } ca, cb;
  ca.s = ma; cb.s = mb;
#pragma unroll
  for (int g = 0; g < 4; ++g) {
    f4_t bw = *(const f4_t*)(bp + g * 4);
    unsigned wl = (g < 2) ? ca.u[2 * g] : cb.u[2 * g - 4];
    unsigned wh = (g < 2) ? ca.u[2 * g + 1] : cb.u[2 * g - 3];
    SA[4 * g + 0] = bw[0] + bflo(wl);
    SA[4 * g + 1] = bw[1] + bfhi(wl);
    SA[4 * g + 2] = bw[2] + bflo(wh);
    SA[4 * g + 3] = bw[3] + bfhi(wh);
  }
}

__device__ inline void packP(f32x16& SA, float& L, bf8_t& F0, bf8_t& F1) {
#pragma unroll
  for (int r = 0; r < 16; ++r) {
    SA[r] = ex2(SA[r]);
    L += SA[r];
  }
  unsigned u0 = pk2(SA[0], SA[1]), u1 = pk2(SA[2], SA[3]);
  unsigned u2 = pk2(SA[4], SA[5]), u3 = pk2(SA[6], SA[7]);
  unsigned u4 = pk2(SA[8], SA[9]), u5 = pk2(SA[10], SA[11]);
  unsigned u6 = pk2(SA[12], SA[13]), u7 = pk2(SA[14], SA[15]);
  swap32(u0, u2); swap32(u1, u3); swap32(u4, u6); swap32(u5, u7);
  union { unsigned u[4]; bf8_t b; } fa, fb;
  fa.u[0] = u0; fa.u[1] = u1; fa.u[2] = u2; fa.u[3] = u3;
  fb.u[0] = u4; fb.u[1] = u5; fb.u[2] = u6; fb.u[3] = u7;
  F0 = fa.b; F1 = fb.b;
}

__global__ __launch_bounds__(256, 3) void flash_attn17(
    const unsigned short* __restrict__ Qb, const unsigned short* __restrict__ Kb,
    const unsigned short* __restrict__ Vt, const unsigned short* __restrict__ maskP,
    const float* __restrict__ biasPf, unsigned short* __restrict__ attn) {
  __shared__ __align__(16) char smem[40960];
  const int tid = threadIdx.x;
  const int w = tid >> 6, lane = tid & 63;
  const int l31 = lane & 31, hi = lane >> 5;
  const int p = w >> 1, qw = (w & 1) * 32;
  const int id = blockIdx.x;
  const int h = id >> 6;            // 0..11
  const int qb = id & 63;
  const int qt = qb >> 1, b = qb & 1;   // XCD = id%8 = qb%8 -> all 12 h share XCD
  const int bh = b * NH + h;
  const int q0 = qt * 64;
  const int q = q0 + qw + l31;      // this lane's query (column of S^T)

  unsigned short* KldsP = (unsigned short*)(smem + p * 16384);  // [64 key][64 d] swizzled
  unsigned short* VldsP = KldsP + 4096;                         // [64 d][64 key] swizzled
  float* biasF = (float*)(smem + 32768);                        // [2048] permuted f32

  {
    const float* srcB = biasPf + bh * 2048 + tid * 8;
    *(f4_t*)&biasF[tid * 8] = *(const f4_t*)srcB;
    *(f4_t*)&biasF[tid * 8 + 4] = *(const f4_t*)(srcB + 4);
  }
  // bias stores must be complete before the first raw barrier (cross-wave reads)
  asm volatile("s_waitcnt lgkmcnt(0)" ::: "memory");

  bf8_t qf[4];
  {
    const unsigned short* qbase = Qb + ((size_t)bh * SEQ + q) * HD + hi * 8;
#pragma unroll
    for (int dk = 0; dk < 4; ++dk) qf[dk] = *(const bf8_t*)(qbase + dk * 16);
  }

  const int li = (w & 1) * 64 + lane;
  const int r0 = li >> 3, cc = li & 7;
  const int dstOff = r0 * 64 + ((cc ^ (r0 & 7)) << 3);
  const unsigned short* kb0 = Kb + (size_t)bh * SEQ * HD + (p * 1024 + r0) * 64 + cc * 8;
  const unsigned short* VtG = Vt + (size_t)bh * HD * SEQ;
  const unsigned short* vb0 = VtG + (size_t)r0 * SEQ + p * 1024 + cc * 8;
  const unsigned short* mpp = maskP + (((size_t)(b * 32 + p * 16) * 2048) + q) * 64 + hi * 16;

  us8_t kpf0, kpf1, kpf2, kpf3, vpf0, vpf1, vpf2, vpf3, mpf0, mpf1, mpf2, mpf3;

#define PF_KV()                                                               \
  asm volatile("global_load_dwordx4 %0, %8, off\n\t"                          \
               "global_load_dwordx4 %1, %8, off offset:2048\n\t"              \
               "global_load_dwordx4 %2, %9, off\n\t"                          \
               "global_load_dwordx4 %3, %9, off offset:2048\n\t"              \
               "global_load_dwordx4 %4, %10, off\n\t"                         \
               "global_load_dwordx4 %5, %11, off\n\t"                         \
               "global_load_dwordx4 %6, %12, off\n\t"                         \
               "global_load_dwordx4 %7, %13, off"                             \
               : "=&v"(kpf0), "=&v"(kpf1), "=&v"(kpf2), "=&v"(kpf3),          \
                 "=&v"(vpf0), "=&v"(vpf1), "=&v"(vpf2), "=&v"(vpf3)           \
               : "v"(kb0), "v"(kb0 + 2048), "v"(vb0), "v"(vb0 + 16 * SEQ),    \
                 "v"(vb0 + 32 * SEQ), "v"(vb0 + 48 * SEQ))

#define PF_M()                                                                \
  asm volatile("global_load_dwordx4 %0, %4, off\n\t"                          \
               "global_load_dwordx4 %1, %4, off offset:16\n\t"                \
               "global_load_dwordx4 %2, %4, off offset:64\n\t"                \
               "global_load_dwordx4 %3, %4, off offset:80"                    \
               : "=&v"(mpf0), "=&v"(mpf1), "=&v"(mpf2), "=&v"(mpf3)           \
               : "v"(mpp))

  PF_KV();
  PF_M();

  f32x16 Oacc0 = {}, Oacc1 = {};   // O^T[d][q], dblk 0/1
  float Lacc = 0.0f;
  const int swzA = l31 & 7;

  for (int it = 0; it < 16; ++it) {
    asm volatile("s_waitcnt vmcnt(4)"   // K/V done; 4 mask loads may still fly
                 : "+v"(kpf0), "+v"(kpf1), "+v"(kpf2), "+v"(kpf3),
                   "+v"(vpf0), "+v"(vpf1), "+v"(vpf2), "+v"(vpf3));
    __builtin_amdgcn_s_barrier();             // barrier1: tile reads done everywhere
    {
      us8_t* kd = (us8_t*)(KldsP + dstOff);
      kd[0] = kpf0; kd[128] = kpf1; kd[256] = kpf2; kd[384] = kpf3;
      us8_t* vd = (us8_t*)(VldsP + dstOff);
      vd[0] = vpf0; vd[128] = vpf1; vd[256] = vpf2; vd[384] = vpf3;
    }
    asm volatile("s_waitcnt lgkmcnt(0)" ::: "memory");  // my LDS writes landed
    __builtin_amdgcn_s_barrier();             // barrier2: tile visible to pair
    __builtin_amdgcn_sched_barrier(0);

    if (it < 15) {
      kb0 += 4096; vb0 += 64;
      PF_KV();
      asm volatile("s_waitcnt vmcnt(8)"  // drain 4 old mask loads, keep 8 new K/V
                   : "+v"(mpf0), "+v"(mpf1), "+v"(mpf2), "+v"(mpf3));
    } else {
      asm volatile("s_waitcnt vmcnt(0)"
                   : "+v"(mpf0), "+v"(mpf1), "+v"(mpf2), "+v"(mpf3));
    }

    // S-accumulator init = bias + mask (both pre-scaled) as MFMA C-in
    const float* bp = biasF + ((p << 4) + it) * 64 + (hi << 4);
    f32x16 s0, s1;
    initS(s0, bp, mpf0, mpf1);
    initS(s1, bp + 32, mpf2, mpf3);

    if (it < 15) { mpp += 131072; PF_M(); }

    // QK^T: S^T[key][q]
    __builtin_amdgcn_s_setprio(1);
#pragma unroll
    for (int dk = 0; dk < 4; ++dk) {
      const int co = ((dk * 2 + hi) ^ swzA) << 3;
      bf8_t k0 = *(const bf8_t*)(KldsP + l31 * 64 + co);
      bf8_t k1 = *(const bf8_t*)(KldsP + (32 + l31) * 64 + co);
      s0 = __builtin_amdgcn_mfma_f32_32x32x16_bf16(k0, qf[dk], s0, 0, 0, 0);
      s1 = __builtin_amdgcn_mfma_f32_32x32x16_bf16(k1, qf[dk], s1, 0, 0, 0);
    }
    __builtin_amdgcn_s_setprio(0);

    // exp2 + in-register P -> bf16 B-fragments
    bf8_t pfr0, pfr1, pfr2, pfr3;
    packP(s0, Lacc, pfr0, pfr1);
    packP(s1, Lacc, pfr2, pfr3);

    // PV: O^T += V^T * P^T
    __builtin_amdgcn_s_setprio(1);
#pragma unroll
    for (int ks = 0; ks < 4; ++ks) {
      const int co = ((ks * 2 + hi) ^ swzA) << 3;
      bf8_t v0 = *(const bf8_t*)(VldsP + l31 * 64 + co);
      bf8_t v1 = *(const bf8_t*)(VldsP + (32 + l31) * 64 + co);
      bf8_t pp = ks == 0 ? pfr0 : ks == 1 ? pfr1 : ks == 2 ? pfr2 : pfr3;
      Oacc0 = __builtin_amdgcn_mfma_f32_32x32x16_bf16(v0, pp, Oacc0, 0, 0, 0);
      Oacc1 = __builtin_amdgcn_mfma_f32_32x32x16_bf16(v1, pp, Oacc1, 0, 0, 0);
    }
    __builtin_amdgcn_s_setprio(0);
  }
#undef PF_KV
#undef PF_M

  // -------- combine pair partials via LDS (additive: fixed shift, no max) ------
  __syncthreads();   // full drain OK here (once)
  {
    float* OfP = (float*)smem + p * (64 * 65);
    const int qr = (qw + l31) * 65;
#pragma unroll
    for (int r = 0; r < 16; ++r) {
      int d = (r & 3) + 8 * (r >> 2) + 4 * hi;
      OfP[qr + d] = Oacc0[r];
      OfP[qr + 32 + d] = Oacc1[r];
    }
    float Lf = Lacc + __shfl_xor(Lacc, 32);
    if (hi == 0) OfP[qr + 64] = Lf;
  }
  __syncthreads();
  {
    const float* O0 = (const float*)smem;
    const float* O1 = O0 + 64 * 65;
    const int ql = tid >> 2, dc = tid & 3;
    const int qr = ql * 65;
    float inv = 1.0f / (O0[qr + 64] + O1[qr + 64]);
    unsigned short* orow = attn + ((size_t)b * SEQ + q0 + ql) * E + h * HD + dc * 16;
    us8_t o0, o1;
#pragma unroll
    for (int i = 0; i < 8; ++i)
      o0[i] = f2bf((O0[qr + dc * 16 + i] + O1[qr + dc * 16 + i]) * inv);
#pragma unroll
    for (int i = 0; i < 8; ++i)
      o1[i] = f2bf((O0[qr + dc * 16 + 8 + i] + O1[qr + dc * 16 + 8 + i]) * inv);
    *(us8_t*)orow = o0;
    *(us8_t*)(orow + 8) = o1;
  }
}

// ---------------- output projection GEMM: 64x128 tile (unchanged from R7) -----
__global__ __launch_bounds__(256) void gemm_out(
    const unsigned short* __restrict__ A, const unsigned short* __restrict__ Bw,
    const float* __restrict__ bo, float* __restrict__ out) {
  __shared__ unsigned short Alds[64 * 64];    // 8 KB
  __shared__ unsigned short Blds[128 * 64];   // 16 KB
  const int w = threadIdx.x >> 6, lane = threadIdx.x & 63;
  const int quad = lane >> 4, l15 = lane & 15;
  const int rowBase = blockIdx.x * 64;
  const int colBase = blockIdx.y * 128;
  const int wr = (w & 1) * 32, wc = (w >> 1) * 64;
  f4_t acc[2][4] = {};
  const int swz = l15 & 7;

  for (int k0 = 0; k0 < E; k0 += 64) {
    __syncthreads();
#pragma unroll
    for (int c = 0; c < 2; ++c) {
      int s = c * 256 + w * 64 + lane;
      int r = s >> 3, col = ((s & 7) ^ (r & 7)) * 8;
      const unsigned short* ga = A + (size_t)(rowBase + r) * E + k0 + col;
      __builtin_amdgcn_global_load_lds((const __attribute__((address_space(1))) void*)ga,
          (__attribute__((address_space(3))) void*)&Alds[c * 2048 + w * 512], 16, 0, 0);
    }
#pragma unroll
    for (int c = 0; c < 4; ++c) {
      int s = c * 256 + w * 64 + lane;
      int r = s >> 3, col = ((s & 7) ^ (r & 7)) * 8;
      const unsigned short* gb = Bw + (size_t)(colBase + r) * E + k0 + col;
      __builtin_amdgcn_global_load_lds((const __attribute__((address_space(1))) void*)gb,
          (__attribute__((address_space(3))) void*)&Blds[c * 2048 + w * 512], 16, 0, 0);
    }
    __builtin_amdgcn_s_waitcnt(0);
    __syncthreads();
    bf8_t af[2][2], bfr[4][2];
#pragma unroll
    for (int mi = 0; mi < 2; ++mi)
#pragma unroll
      for (int ks = 0; ks < 2; ++ks)
        af[mi][ks] = *(const bf8_t*)&Alds[(wr + mi * 16 + l15) * 64 + (((ks * 4 + quad) ^ swz) << 3)];
#pragma unroll
    for (int ni = 0; ni < 4; ++ni)
#pragma unroll
      for (int ks = 0; ks < 2; ++ks)
        bfr[ni][ks] = *(const bf8_t*)&Blds[(wc + ni * 16 + l15) * 64 + (((ks * 4 + quad) ^ swz) << 3)];
#pragma unroll
    for (int ks = 0; ks < 2; ++ks)
#pragma unroll
      for (int mi = 0; mi < 2; ++mi)
#pragma unroll
        for (int ni = 0; ni < 4; ++ni)
          acc[mi][ni] = __builtin_amdgcn_mfma_f32_16x16x32_bf16(af[mi][ks], bfr[ni][ks], acc[mi][ni], 0, 0, 0);
  }

#pragma unroll
  for (int mi = 0; mi < 2; ++mi) {
#pragma unroll
    for (int ni = 0; ni < 4; ++ni) {
      int gn = colBase + wc + ni * 16 + l15;
      float bias = bo[gn];
#pragma unroll
      for (int r = 0; r < 4; ++r) {
        int gm = rowBase + wr + mi * 16 + quad * 4 + r;
        out[(size_t)gm * E + gn] = acc[mi][ni][r] + bias;
      }
    }
  }
}

extern "C" void kernel_launch(void* const* d_in, const int* in_sizes, int n_in,
                              void* d_out, int out_size, void* d_ws, size_t ws_size,
                              hipStream_t stream) {
  const float* hidden = (const float*)d_in[0];
  const float* mask = (const float*)d_in[1];
  const float* abias = (const float*)d_in[2];
  const float* Wq = (const float*)d_in[3];
  const float* bq = (const float*)d_in[4];
  const float* Wk = (const float*)d_in[5];
  const float* bk = (const float*)d_in[6];
  const float* Wv = (const float*)d_in[7];
  const float* bv = (const float*)d_in[8];
  const float* Wo = (const float*)d_in[9];
  const float* bo = (const float*)d_in[10];
  const float* beta = (const float*)d_in[11];
  const float* betaBias = (const float*)d_in[12];
  float* out = (float*)d_out;

  char* ws = (char*)d_ws;
  unsigned short* Xbf = (unsigned short*)(ws);
  unsigned short* Wqkv = (unsigned short*)(ws + 6291456);
  unsigned short* Wobf = (unsigned short*)(ws + 9830400);
  unsigned short* Qbuf = (unsigned short*)(ws + 11010048);
  unsigned short* Kbuf = (unsigned short*)(ws + 17301504);
  unsigned short* Vtb = (unsigned short*)(ws + 23592960);
  unsigned short* Maskbf = (unsigned short*)(ws + 29884416);  // 16.78 MB
  float* BiasP = (float*)(ws + 46661632);   // 24*2048*4 = 192 KB
  unsigned short* Attn = Xbf;  // Xbf dead after gemm_qkv

  cvt_all<<<6808, 256, 0, stream>>>(hidden, Wq, Wk, Wv, Wo, mask, abias, beta, betaBias,
                                    Xbf, Wqkv, Wobf, Maskbf, BiasP);
  gemm_qkv<<<dim3(32, 18), 256, 0, stream>>>(Xbf, Wqkv, bq, bk, bv, Qbuf, Kbuf, Vtb);
  flash_attn17<<<768, 256, 0, stream>>>(Qbuf, Kbuf, Vtb, Maskbf, BiasP, Attn);
  gemm_out<<<dim3(64, 6), 256, 0, stream>>>(Attn, Wobf, bo, out);
}